// Round 2
// baseline (776.670 us; speedup 1.0000x reference)
//
#include <hip/hip_runtime.h>

#define BQ 8
#define TT 1024
#define CC 768
#define NH 12
#define HD 64
#define BH (BQ*NH)      // 96
#define MROWS (BQ*TT)   // 8192
#define NQKV (3*CC)     // 2304
#define KD CC           // 768

typedef unsigned short u16;
typedef __attribute__((ext_vector_type(4))) short short4v;
typedef __attribute__((ext_vector_type(8))) short short8v;
typedef __attribute__((ext_vector_type(4))) float floatx4;

__device__ __forceinline__ float bf2f(u16 u) {
  union { unsigned int i; float f; } c; c.i = ((unsigned int)u) << 16; return c.f;
}
__device__ __forceinline__ u16 f2bf(float f) {
  union { float f; unsigned int i; } c; c.f = f;
  unsigned int i = c.i;
  return (u16)((i + 0x7FFFu + ((i >> 16) & 1u)) >> 16);  // RNE
}

// ---------------- elementwise f32 -> bf16 (n multiple of 1024) ----------------
__global__ __launch_bounds__(256) void convert_f32_bf16(
    const float* __restrict__ in, u16* __restrict__ out, int n)
{
  int i = (blockIdx.x * 256 + threadIdx.x) * 4;
  if (i >= n) return;
  floatx4 v = *(const floatx4*)(in + i);
  short4v o;
  o[0] = (short)f2bf(v[0]); o[1] = (short)f2bf(v[1]);
  o[2] = (short)f2bf(v[2]); o[3] = (short)f2bf(v[3]);
  *(short4v*)(out + i) = o;
}

// ---------- transpose f32 [R,Cc] -> bf16 [Cc,R]: out[c*R+r] = in[r*Cc+c] ----------
__global__ __launch_bounds__(256) void transpose_f32_bf16(
    const float* __restrict__ in, u16* __restrict__ out, int R, int Cc)
{
  __shared__ float tile[32][33];
  int ct = Cc >> 5;
  int bx = blockIdx.x % ct;
  int by = blockIdx.x / ct;
  int tx = threadIdx.x & 31;
  int ty = threadIdx.x >> 5;    // 0..7
  int c0 = bx << 5, r0 = by << 5;
#pragma unroll
  for (int s = 0; s < 4; ++s)
    tile[ty + s*8][tx] = in[(size_t)(r0 + ty + s*8) * Cc + c0 + tx];
  __syncthreads();
#pragma unroll
  for (int s = 0; s < 4; ++s)
    out[(size_t)(c0 + ty + s*8) * R + r0 + tx] = f2bf(tile[tx][ty + s*8]);
}

// ---------------- GEMM: C[M,N] = A[M,K] * Bt[N,K]^T + bias (f32) ----------------
// mode 0: scatter into q/k/v [B,H,T,HD] bf16.  mode 1: f32 row-major out.
#define LDK 40   // 32 + 8 pad shorts

__global__ __launch_bounds__(256) void gemm_bt(
    const u16* __restrict__ A, const u16* __restrict__ Bt,
    const float* __restrict__ bias,
    float* __restrict__ out,
    u16* __restrict__ qo, u16* __restrict__ ko, u16* __restrict__ vo,
    int M, int N, int mode)
{
  const int K = KD;
  __shared__ u16 As[64 * LDK];
  __shared__ u16 Bs[64 * LDK];
  int tid = threadIdx.x;
  int lane = tid & 63;
  int wave = tid >> 6;
  int wr = (wave >> 1) << 5;   // 0 or 32
  int wc = (wave & 1) << 5;
  int mtiles = M >> 6;
  int mt = blockIdx.x % mtiles;
  int nt = blockIdx.x / mtiles;
  int m0 = mt << 6, n0 = nt << 6;

  int srow = tid >> 2;
  int scol = (tid & 3) << 3;
  const u16* ag = A + (size_t)(m0 + srow) * K + scol;
  const u16* bg = Bt + (size_t)(n0 + srow) * K + scol;
  u16* asw = &As[srow * LDK + scol];
  u16* bsw = &Bs[srow * LDK + scol];

  int lr = lane & 15;
  int lq = lane >> 4;
  const u16* ar0 = &As[(wr + lr) * LDK + lq * 4];
  const u16* ar1 = ar0 + (LDK << 4);     // +16 rows
  const u16* br0 = &Bs[(wc + lr) * LDK + lq * 4];
  const u16* br1 = br0 + (LDK << 4);

  floatx4 z = {0.f, 0.f, 0.f, 0.f};
  floatx4 acc00 = z, acc01 = z, acc10 = z, acc11 = z;

  for (int kt = 0; kt < K; kt += 32) {
    *(short8v*)asw = *(const short8v*)(ag + kt);
    *(short8v*)bsw = *(const short8v*)(bg + kt);
    __syncthreads();
    short4v a0l = *(const short4v*)(ar0);
    short4v a0h = *(const short4v*)(ar0 + 16);
    short4v a1l = *(const short4v*)(ar1);
    short4v a1h = *(const short4v*)(ar1 + 16);
    short4v b0l = *(const short4v*)(br0);
    short4v b0h = *(const short4v*)(br0 + 16);
    short4v b1l = *(const short4v*)(br1);
    short4v b1h = *(const short4v*)(br1 + 16);
    acc00 = __builtin_amdgcn_mfma_f32_16x16x16bf16_1k(a0l, b0l, acc00, 0, 0, 0);
    acc01 = __builtin_amdgcn_mfma_f32_16x16x16bf16_1k(a0l, b1l, acc01, 0, 0, 0);
    acc10 = __builtin_amdgcn_mfma_f32_16x16x16bf16_1k(a1l, b0l, acc10, 0, 0, 0);
    acc11 = __builtin_amdgcn_mfma_f32_16x16x16bf16_1k(a1l, b1l, acc11, 0, 0, 0);
    acc00 = __builtin_amdgcn_mfma_f32_16x16x16bf16_1k(a0h, b0h, acc00, 0, 0, 0);
    acc01 = __builtin_amdgcn_mfma_f32_16x16x16bf16_1k(a0h, b1h, acc01, 0, 0, 0);
    acc10 = __builtin_amdgcn_mfma_f32_16x16x16bf16_1k(a1h, b0h, acc10, 0, 0, 0);
    acc11 = __builtin_amdgcn_mfma_f32_16x16x16bf16_1k(a1h, b1h, acc11, 0, 0, 0);
    __syncthreads();
  }

  floatx4 accs[2][2] = {{acc00, acc01}, {acc10, acc11}};
#pragma unroll
  for (int i = 0; i < 2; ++i) {
#pragma unroll
    for (int j = 0; j < 2; ++j) {
      int nn = n0 + wc + j * 16 + lr;
      float bv = bias[nn];
#pragma unroll
      for (int r = 0; r < 4; ++r) {
        int mm = m0 + wr + i * 16 + lq * 4 + r;
        float val = accs[i][j][r] + bv;
        if (mode == 0) {
          int bb = mm >> 10, tt = mm & 1023;
          int which = nn / CC;
          int rem = nn - which * CC;
          int hh = rem >> 6, dd = rem & 63;
          size_t idx = (((size_t)(bb * NH + hh)) * TT + tt) * HD + dd;
          u16* dst = (which == 0) ? qo : ((which == 1) ? ko : vo);
          dst[idx] = f2bf(val);
        } else {
          out[(size_t)mm * N + nn] = val;
        }
      }
    }
  }
}

// ---------------- mean of V over T, per (b,h,d) ----------------
__global__ __launch_bounds__(64) void vmean_kernel(
    const u16* __restrict__ vb, float* __restrict__ mv)
{
  int bh = blockIdx.x;
  int d = threadIdx.x;
  const u16* p = vb + (size_t)bh * TT * HD + d;
  float s0 = 0.f, s1 = 0.f, s2 = 0.f, s3 = 0.f;
  for (int t = 0; t < TT; t += 4) {
    s0 += bf2f(p[(size_t)(t + 0) * HD]);
    s1 += bf2f(p[(size_t)(t + 1) * HD]);
    s2 += bf2f(p[(size_t)(t + 2) * HD]);
    s3 += bf2f(p[(size_t)(t + 3) * HD]);
  }
  mv[bh * HD + d] = (s0 + s1 + s2 + s3) * (1.0f / 1024.0f);
}

// ---------------- attention: causal online-softmax, VALU baseline ----------------
#define LDKV 68
#define LDP 65

__global__ __launch_bounds__(256) void attn_kernel(
    const u16* __restrict__ qb, const u16* __restrict__ kb,
    const u16* __restrict__ vb, const int* __restrict__ mask,
    const float* __restrict__ meanv, u16* __restrict__ outb)
{
  __shared__ float Kt[64 * LDKV];
  __shared__ float Vt[64 * LDKV];
  __shared__ float Pt[64 * LDP];

  int tid = threadIdx.x;
  int lane = tid & 63;
  int w = tid >> 6;
  int g = lane & 3;          // dim group (16 dims)
  int lr = lane >> 2;        // row within wave (16 rows/wave)
  int row = (w << 4) + lr;   // 0..63 within q-tile

  int qt = blockIdx.x & 15;
  int bh = blockIdx.x >> 4;  // 0..95
  int b = bh / NH;
  int h = bh - b * NH;
  int qrow = (qt << 6) + row;

  // q fragment, pre-scaled by 1/sqrt(HD)
  float qr[16];
  {
    const u16* qsrc = qb + ((size_t)bh * TT + qrow) * HD + (g << 4);
    short8v q0 = *(const short8v*)qsrc;
    short8v q1 = *(const short8v*)(qsrc + 8);
#pragma unroll
    for (int ii = 0; ii < 8; ++ii) {
      qr[ii]     = bf2f((u16)q0[ii]) * 0.125f;
      qr[ii + 8] = bf2f((u16)q1[ii]) * 0.125f;
    }
  }

  float o[16];
#pragma unroll
  for (int d = 0; d < 16; ++d) o[d] = 0.f;
  float m_i = -INFINITY, l_i = 0.f;

  int srow = tid >> 2;
  int scol = (tid & 3) << 4;
  const u16* kst = kb + (size_t)bh * TT * HD + srow * HD + scol;
  const u16* vst = vb + (size_t)bh * TT * HD + srow * HD + scol;
  float* kdst = &Kt[srow * LDKV + scol];
  float* vdst = &Vt[srow * LDKV + scol];

  for (int kt = 0; kt <= qt; ++kt) {
    {  // stage K,V tiles (bf16 -> f32)
      const u16* kp = kst + (size_t)(kt << 6) * HD;
      const u16* vp = vst + (size_t)(kt << 6) * HD;
      short8v k0 = *(const short8v*)kp;
      short8v k1 = *(const short8v*)(kp + 8);
      short8v v0 = *(const short8v*)vp;
      short8v v1 = *(const short8v*)(vp + 8);
#pragma unroll
      for (int ii = 0; ii < 8; ++ii) {
        kdst[ii]     = bf2f((u16)k0[ii]);
        kdst[ii + 8] = bf2f((u16)k1[ii]);
        vdst[ii]     = bf2f((u16)v0[ii]);
        vdst[ii + 8] = bf2f((u16)v1[ii]);
      }
    }
    __syncthreads();

    // Pass 1: scores for 64 keys; lane keeps keys [g*16, g*16+16)
    float sreg[16];
    float tmax = -INFINITY;
    int kbase = kt << 6;
#pragma unroll
    for (int j = 0; j < 64; ++j) {
      const floatx4* krow = (const floatx4*)&Kt[j * LDKV + (g << 4)];
      floatx4 k0 = krow[0], k1 = krow[1], k2 = krow[2], k3 = krow[3];
      float part = qr[0]*k0[0] + qr[1]*k0[1] + qr[2]*k0[2] + qr[3]*k0[3]
                 + qr[4]*k1[0] + qr[5]*k1[1] + qr[6]*k1[2] + qr[7]*k1[3]
                 + qr[8]*k2[0] + qr[9]*k2[1] + qr[10]*k2[2] + qr[11]*k2[3]
                 + qr[12]*k3[0] + qr[13]*k3[1] + qr[14]*k3[2] + qr[15]*k3[3];
      float s = part;
      s += __shfl_xor(s, 1);
      s += __shfl_xor(s, 2);          // full dot in all 4 lanes of the row
      if (kbase + j > qrow) s = -INFINITY;   // causal
      if ((j >> 4) == g) sreg[j & 15] = s;
      tmax = fmaxf(tmax, s);
    }

    float m_new = fmaxf(m_i, tmax);
    float alpha = __expf(m_i - m_new);
    float psum = 0.f;
    float* prow = &Pt[row * LDP + (g << 4)];
#pragma unroll
    for (int jj = 0; jj < 16; ++jj) {
      float p = __expf(sreg[jj] - m_new);
      psum += p;
      prow[jj] = p;
    }
    psum += __shfl_xor(psum, 1);
    psum += __shfl_xor(psum, 2);
    l_i = l_i * alpha + psum;
    m_i = m_new;
#pragma unroll
    for (int d = 0; d < 16; ++d) o[d] *= alpha;

    __syncthreads();   // ensure P visible before PV pass

    // Pass 2: O += P * V
#pragma unroll 8
    for (int j = 0; j < 64; ++j) {
      float pj = Pt[row * LDP + j];
      const floatx4* vrow = (const floatx4*)&Vt[j * LDKV + (g << 4)];
      floatx4 v0 = vrow[0], v1 = vrow[1], v2 = vrow[2], v3 = vrow[3];
      o[0]  += pj * v0[0]; o[1]  += pj * v0[1]; o[2]  += pj * v0[2]; o[3]  += pj * v0[3];
      o[4]  += pj * v1[0]; o[5]  += pj * v1[1]; o[6]  += pj * v1[2]; o[7]  += pj * v1[3];
      o[8]  += pj * v2[0]; o[9]  += pj * v2[1]; o[10] += pj * v2[2]; o[11] += pj * v2[3];
      o[12] += pj * v3[0]; o[13] += pj * v3[1]; o[14] += pj * v3[2]; o[15] += pj * v3[3];
    }
    __syncthreads();
  }

  float inv = 1.f / l_i;
  bool masked = (mask[b * TT + qrow] == 0);
  const float* mvp = meanv + bh * HD + (g << 4);
  u16 ob[16];
#pragma unroll
  for (int d = 0; d < 16; ++d) {
    float val = masked ? mvp[d] : o[d] * inv;
    ob[d] = f2bf(val);
  }
  u16* dst = outb + ((size_t)(b * TT + qrow)) * CC + h * HD + (g << 4);
#pragma unroll
  for (int i = 0; i < 4; ++i) {
    short4v pack;
    pack[0] = (short)ob[i*4 + 0];
    pack[1] = (short)ob[i*4 + 1];
    pack[2] = (short)ob[i*4 + 2];
    pack[3] = (short)ob[i*4 + 3];
    *(short4v*)(dst + i*4) = pack;
  }
}

// ---------------- launcher ----------------
extern "C" void kernel_launch(void* const* d_in, const int* in_sizes, int n_in,
                              void* d_out, int out_size, void* d_ws, size_t ws_size,
                              hipStream_t stream)
{
  (void)in_sizes; (void)n_in; (void)out_size; (void)ws_size;
  const float* x     = (const float*)d_in[0];   // [B,T,C] f32
  const int*   mask  = (const int*)d_in[1];     // [B,T] i32
  const float* Wattn = (const float*)d_in[2];   // [C,3C] f32
  const float* battn = (const float*)d_in[3];   // [3C] f32
  const float* Wproj = (const float*)d_in[4];   // [C,C] f32
  const float* bproj = (const float*)d_in[5];   // [C] f32
  float* out = (float*)d_out;                   // [B,T,C] f32

  char* ws = (char*)d_ws;
  size_t off = 0;
  auto alloc = [&](size_t bytes) -> void* {
    void* p = ws + off;
    off += (bytes + 255) & ~(size_t)255;
    return p;
  };
  u16* WtA  = (u16*)alloc((size_t)NQKV * KD * 2);    // [2304,768] bf16
  u16* WtP  = (u16*)alloc((size_t)CC * CC * 2);      // [768,768] bf16
  u16* xb   = (u16*)alloc((size_t)MROWS * CC * 2);   // [B*T,C] bf16
  u16* qbuf = (u16*)alloc((size_t)MROWS * CC * 2);   // [B,H,T,HD] bf16
  u16* kbuf = (u16*)alloc((size_t)MROWS * CC * 2);
  u16* vbuf = (u16*)alloc((size_t)MROWS * CC * 2);
  u16* abuf = (u16*)alloc((size_t)MROWS * CC * 2);   // [B,T,H*HD] bf16
  float* mv = (float*)alloc((size_t)BH * HD * 4);

  int nx = MROWS * CC;
  convert_f32_bf16<<<nx / (256 * 4), 256, 0, stream>>>(x, xb, nx);
  transpose_f32_bf16<<<(NQKV/32)*(KD/32), 256, 0, stream>>>(Wattn, WtA, KD, NQKV);
  transpose_f32_bf16<<<(CC/32)*(CC/32),   256, 0, stream>>>(Wproj, WtP, CC, CC);

  gemm_bt<<<(MROWS/64)*(NQKV/64), 256, 0, stream>>>(
      xb, WtA, battn, nullptr, qbuf, kbuf, vbuf, MROWS, NQKV, 0);

  vmean_kernel<<<BH, 64, 0, stream>>>(vbuf, mv);

  attn_kernel<<<BH * (TT/64), 256, 0, stream>>>(qbuf, kbuf, vbuf, mask, mv, abuf);

  gemm_bt<<<(MROWS/64)*(CC/64), 256, 0, stream>>>(
      abuf, WtP, bproj, out, nullptr, nullptr, nullptr, MROWS, CC, 1);
}

// Round 3
// 309.358 us; speedup vs baseline: 2.5106x; 2.5106x over previous
//
#include <hip/hip_runtime.h>

#define BQ 8
#define TT 1024
#define CC 768
#define NH 12
#define HD 64
#define BH (BQ*NH)      // 96
#define MROWS (BQ*TT)   // 8192
#define NQKV (3*CC)     // 2304
#define KD CC           // 768

typedef unsigned short u16;
typedef __attribute__((ext_vector_type(4))) short short4v;
typedef __attribute__((ext_vector_type(8))) short short8v;
typedef __attribute__((ext_vector_type(4))) float floatx4;

__device__ __forceinline__ float bf2f(u16 u) {
  union { unsigned int i; float f; } c; c.i = ((unsigned int)u) << 16; return c.f;
}
__device__ __forceinline__ u16 f2bf(float f) {
  union { float f; unsigned int i; } c; c.f = f;
  unsigned int i = c.i;
  return (u16)((i + 0x7FFFu + ((i >> 16) & 1u)) >> 16);  // RNE
}

// ---------------- elementwise f32 -> bf16 ----------------
__global__ __launch_bounds__(256) void convert_f32_bf16(
    const float* __restrict__ in, u16* __restrict__ out, int n)
{
  int i = (blockIdx.x * 256 + threadIdx.x) * 4;
  if (i >= n) return;
  floatx4 v = *(const floatx4*)(in + i);
  short4v o;
  o[0] = (short)f2bf(v[0]); o[1] = (short)f2bf(v[1]);
  o[2] = (short)f2bf(v[2]); o[3] = (short)f2bf(v[3]);
  *(short4v*)(out + i) = o;
}

// ---------- transpose f32 [R,Cc] -> bf16 [Cc,R] ----------
__global__ __launch_bounds__(256) void transpose_f32_bf16(
    const float* __restrict__ in, u16* __restrict__ out, int R, int Cc)
{
  __shared__ float tile[32][33];
  int ct = Cc >> 5;
  int bx = blockIdx.x % ct;
  int by = blockIdx.x / ct;
  int tx = threadIdx.x & 31;
  int ty = threadIdx.x >> 5;    // 0..7
  int c0 = bx << 5, r0 = by << 5;
#pragma unroll
  for (int s = 0; s < 4; ++s)
    tile[ty + s*8][tx] = in[(size_t)(r0 + ty + s*8) * Cc + c0 + tx];
  __syncthreads();
#pragma unroll
  for (int s = 0; s < 4; ++s)
    out[(size_t)(c0 + ty + s*8) * R + r0 + tx] = f2bf(tile[tx][ty + s*8]);
}

// ---------------- GEMM: C[M,N] = A[M,K] * Bt[N,K]^T + bias (f32) ----------------
#define LDK 40

__global__ __launch_bounds__(256) void gemm_bt(
    const u16* __restrict__ A, const u16* __restrict__ Bt,
    const float* __restrict__ bias,
    float* __restrict__ out,
    u16* __restrict__ qo, u16* __restrict__ ko, u16* __restrict__ vo,
    int M, int N, int mode)
{
  const int K = KD;
  __shared__ u16 As[64 * LDK];
  __shared__ u16 Bs[64 * LDK];
  int tid = threadIdx.x;
  int lane = tid & 63;
  int wave = tid >> 6;
  int wr = (wave >> 1) << 5;
  int wc = (wave & 1) << 5;
  int mtiles = M >> 6;
  int mt = blockIdx.x % mtiles;
  int nt = blockIdx.x / mtiles;
  int m0 = mt << 6, n0 = nt << 6;

  int srow = tid >> 2;
  int scol = (tid & 3) << 3;
  const u16* ag = A + (size_t)(m0 + srow) * K + scol;
  const u16* bg = Bt + (size_t)(n0 + srow) * K + scol;
  u16* asw = &As[srow * LDK + scol];
  u16* bsw = &Bs[srow * LDK + scol];

  int lr = lane & 15;
  int lq = lane >> 4;
  const u16* ar0 = &As[(wr + lr) * LDK + lq * 4];
  const u16* ar1 = ar0 + (LDK << 4);
  const u16* br0 = &Bs[(wc + lr) * LDK + lq * 4];
  const u16* br1 = br0 + (LDK << 4);

  floatx4 z = {0.f, 0.f, 0.f, 0.f};
  floatx4 acc00 = z, acc01 = z, acc10 = z, acc11 = z;

  for (int kt = 0; kt < K; kt += 32) {
    *(short8v*)asw = *(const short8v*)(ag + kt);
    *(short8v*)bsw = *(const short8v*)(bg + kt);
    __syncthreads();
    short4v a0l = *(const short4v*)(ar0);
    short4v a0h = *(const short4v*)(ar0 + 16);
    short4v a1l = *(const short4v*)(ar1);
    short4v a1h = *(const short4v*)(ar1 + 16);
    short4v b0l = *(const short4v*)(br0);
    short4v b0h = *(const short4v*)(br0 + 16);
    short4v b1l = *(const short4v*)(br1);
    short4v b1h = *(const short4v*)(br1 + 16);
    acc00 = __builtin_amdgcn_mfma_f32_16x16x16bf16_1k(a0l, b0l, acc00, 0, 0, 0);
    acc01 = __builtin_amdgcn_mfma_f32_16x16x16bf16_1k(a0l, b1l, acc01, 0, 0, 0);
    acc10 = __builtin_amdgcn_mfma_f32_16x16x16bf16_1k(a1l, b0l, acc10, 0, 0, 0);
    acc11 = __builtin_amdgcn_mfma_f32_16x16x16bf16_1k(a1l, b1l, acc11, 0, 0, 0);
    acc00 = __builtin_amdgcn_mfma_f32_16x16x16bf16_1k(a0h, b0h, acc00, 0, 0, 0);
    acc01 = __builtin_amdgcn_mfma_f32_16x16x16bf16_1k(a0h, b1h, acc01, 0, 0, 0);
    acc10 = __builtin_amdgcn_mfma_f32_16x16x16bf16_1k(a1h, b0h, acc10, 0, 0, 0);
    acc11 = __builtin_amdgcn_mfma_f32_16x16x16bf16_1k(a1h, b1h, acc11, 0, 0, 0);
    __syncthreads();
  }

  floatx4 accs[2][2] = {{acc00, acc01}, {acc10, acc11}};
#pragma unroll
  for (int i = 0; i < 2; ++i) {
#pragma unroll
    for (int j = 0; j < 2; ++j) {
      int nn = n0 + wc + j * 16 + lr;
      float bv = bias[nn];
#pragma unroll
      for (int r = 0; r < 4; ++r) {
        int mm = m0 + wr + i * 16 + lq * 4 + r;
        float val = accs[i][j][r] + bv;
        if (mode == 0) {
          int bb = mm >> 10, tt = mm & 1023;
          int which = nn / CC;
          int rem = nn - which * CC;
          int hh = rem >> 6, dd = rem & 63;
          size_t idx = (((size_t)(bb * NH + hh)) * TT + tt) * HD + dd;
          u16* dst = (which == 0) ? qo : ((which == 1) ? ko : vo);
          dst[idx] = f2bf(val);
        } else {
          out[(size_t)mm * N + nn] = val;
        }
      }
    }
  }
}

// ---------------- V transpose: vbuf [bh][t][d] -> vtb [bh][d][t] ----------------
__global__ __launch_bounds__(256) void transpose_v(
    const u16* __restrict__ vb, u16* __restrict__ vt)
{
  __shared__ u16 tile[64][72];
  int tid = threadIdx.x;
  int tt0 = (blockIdx.x & 15) << 6;
  int bh = blockIdx.x >> 4;
  {
    int trow = tid >> 2;
    int dchunk = (tid & 3) << 4;
    const u16* src = vb + (((size_t)bh * TT + tt0 + trow) * HD) + dchunk;
    *(short8v*)&tile[trow][dchunk]     = *(const short8v*)src;
    *(short8v*)&tile[trow][dchunk + 8] = *(const short8v*)(src + 8);
  }
  __syncthreads();
  {
    int drow = tid >> 2;
    int tchunk = (tid & 3) << 4;
    short8v a, bv;
#pragma unroll
    for (int j = 0; j < 8; ++j) {
      a[j]  = (short)tile[tchunk + j][drow];
      bv[j] = (short)tile[tchunk + 8 + j][drow];
    }
    u16* dst = vt + ((size_t)bh * HD + drow) * TT + tt0 + tchunk;
    *(short8v*)dst       = a;
    *(short8v*)(dst + 8) = bv;
  }
}

// ---------------- mean of V over T, per (b,h,d) ----------------
__global__ __launch_bounds__(64) void vmean_kernel(
    const u16* __restrict__ vb, float* __restrict__ mv)
{
  int bh = blockIdx.x;
  int d = threadIdx.x;
  const u16* p = vb + (size_t)bh * TT * HD + d;
  float s0 = 0.f, s1 = 0.f, s2 = 0.f, s3 = 0.f;
  for (int t = 0; t < TT; t += 4) {
    s0 += bf2f(p[(size_t)(t + 0) * HD]);
    s1 += bf2f(p[(size_t)(t + 1) * HD]);
    s2 += bf2f(p[(size_t)(t + 2) * HD]);
    s3 += bf2f(p[(size_t)(t + 3) * HD]);
  }
  mv[bh * HD + d] = (s0 + s1 + s2 + s3) * (1.0f / 1024.0f);
}

// ---------------- MFMA flash attention ----------------
// Block: 64 q-rows (4 waves x 16 rows). K-tiles of 64 keys.
// Layouts (verified): A/B frag [idx=lane&15][k=quad*8+j]; C/D col=lane&15, row=quad*4+reg.
#define LDW 72   // LDS row stride in shorts (144 B, 16B-aligned, uniform bank load)

__global__ __launch_bounds__(256) void attn_kernel(
    const u16* __restrict__ qb, const u16* __restrict__ kb,
    const u16* __restrict__ vtb, const int* __restrict__ mask,
    const float* __restrict__ meanv, u16* __restrict__ outb)
{
  __shared__ u16 Ks[64 * LDW];       // K tile [key][d]
  __shared__ u16 Vs[64 * LDW];       // V^T tile [d][key]
  __shared__ u16 Ps[4][16 * LDW];    // per-wave P [row][key]

  int tid = threadIdx.x;
  int lane = tid & 63;
  int w = tid >> 6;
  int c = lane & 15;     // fragment index (col)
  int q4 = lane >> 4;    // quad 0..3

  int qt = blockIdx.x & 15;
  int bh = blockIdx.x >> 4;
  int b = bh / NH;
  int h = bh - b * NH;
  int rowbase = (qt << 6) + (w << 4);    // wave's first q-row

  // Q A-fragments: qfrag[kc] = Q[rowbase+c][kc*32 + q4*8 + j]
  short8v qfrag[2];
  {
    const u16* qp = qb + ((size_t)bh * TT + rowbase + c) * HD + q4 * 8;
    qfrag[0] = *(const short8v*)qp;
    qfrag[1] = *(const short8v*)(qp + 32);
  }

  floatx4 o[4];
#pragma unroll
  for (int i = 0; i < 4; ++i) o[i] = (floatx4){0.f, 0.f, 0.f, 0.f};
  float m_i[4], l_i[4];
#pragma unroll
  for (int r = 0; r < 4; ++r) { m_i[r] = -INFINITY; l_i[r] = 0.f; }

  // staging addresses: thread stages 32 B of K row and 32 B of Vt row
  int srow = tid >> 2;
  int schunk = (tid & 3) << 4;
  const u16* kgp = kb + ((size_t)bh * TT + srow) * HD + schunk;
  const u16* vgp = vtb + ((size_t)bh * HD + srow) * TT + schunk;
  u16* ksw = &Ks[srow * LDW + schunk];
  u16* vsw = &Vs[srow * LDW + schunk];
  u16* pw = &Ps[w][0];

  for (int kt = 0; kt <= qt; ++kt) {
    int kbase = kt << 6;
    __syncthreads();
    {
      const u16* kp = kgp + (size_t)kbase * HD;
      const u16* vp = vgp + kbase;
      short8v k0 = *(const short8v*)kp;
      short8v k1 = *(const short8v*)(kp + 8);
      short8v v0 = *(const short8v*)vp;
      short8v v1 = *(const short8v*)(vp + 8);
      *(short8v*)ksw = k0; *(short8v*)(ksw + 8) = k1;
      *(short8v*)vsw = v0; *(short8v*)(vsw + 8) = v1;
    }
    __syncthreads();

    // QK^T: s[nt] = S[row][key=nt*16+c], accumulate over d (2 chunks of 32)
    floatx4 s[4];
#pragma unroll
    for (int nt = 0; nt < 4; ++nt) s[nt] = (floatx4){0.f, 0.f, 0.f, 0.f};
#pragma unroll
    for (int kc = 0; kc < 2; ++kc) {
#pragma unroll
      for (int nt = 0; nt < 4; ++nt) {
        short8v kf = *(const short8v*)&Ks[(nt * 16 + c) * LDW + kc * 32 + q4 * 8];
        s[nt] = __builtin_amdgcn_mfma_f32_16x16x32_bf16(qfrag[kc], kf, s[nt], 0, 0, 0);
      }
    }

    // scale + causal mask (diag tile only)
    if (kt == qt) {
#pragma unroll
      for (int nt = 0; nt < 4; ++nt)
#pragma unroll
        for (int r = 0; r < 4; ++r) {
          float sv = s[nt][r] * 0.125f;
          if (nt * 16 + c > (w << 4) + q4 * 4 + r) sv = -INFINITY;
          s[nt][r] = sv;
        }
    } else {
#pragma unroll
      for (int nt = 0; nt < 4; ++nt)
#pragma unroll
        for (int r = 0; r < 4; ++r) s[nt][r] *= 0.125f;
    }

    // row max over 64 keys: per reg, 4 tiles then 16-lane butterfly
    float mt[4];
#pragma unroll
    for (int r = 0; r < 4; ++r)
      mt[r] = fmaxf(fmaxf(s[0][r], s[1][r]), fmaxf(s[2][r], s[3][r]));
#pragma unroll
    for (int r = 0; r < 4; ++r) {
      mt[r] = fmaxf(mt[r], __shfl_xor(mt[r], 1));
      mt[r] = fmaxf(mt[r], __shfl_xor(mt[r], 2));
      mt[r] = fmaxf(mt[r], __shfl_xor(mt[r], 4));
      mt[r] = fmaxf(mt[r], __shfl_xor(mt[r], 8));
    }

    float al[4];
#pragma unroll
    for (int r = 0; r < 4; ++r) {
      float mn = fmaxf(m_i[r], mt[r]);
      al[r] = __expf(m_i[r] - mn);
      m_i[r] = mn;
    }

    float ps[4] = {0.f, 0.f, 0.f, 0.f};
#pragma unroll
    for (int nt = 0; nt < 4; ++nt)
#pragma unroll
      for (int r = 0; r < 4; ++r) {
        float p = __expf(s[nt][r] - m_i[r]);
        ps[r] += p;
        pw[(q4 * 4 + r) * LDW + nt * 16 + c] = f2bf(p);
      }
#pragma unroll
    for (int r = 0; r < 4; ++r) {
      ps[r] += __shfl_xor(ps[r], 1);
      ps[r] += __shfl_xor(ps[r], 2);
      ps[r] += __shfl_xor(ps[r], 4);
      ps[r] += __shfl_xor(ps[r], 8);
      l_i[r] = l_i[r] * al[r] + ps[r];
    }
#pragma unroll
    for (int nt = 0; nt < 4; ++nt)
#pragma unroll
      for (int r = 0; r < 4; ++r) o[nt][r] *= al[r];

    // PV: O[row][d=nt*16+c] += P[row][key] * Vt[d][key]  (P wave-private, no barrier)
#pragma unroll
    for (int kc = 0; kc < 2; ++kc) {
      short8v pf = *(const short8v*)&pw[c * LDW + kc * 32 + q4 * 8];
#pragma unroll
      for (int nt = 0; nt < 4; ++nt) {
        short8v vf = *(const short8v*)&Vs[(nt * 16 + c) * LDW + kc * 32 + q4 * 8];
        o[nt] = __builtin_amdgcn_mfma_f32_16x16x32_bf16(pf, vf, o[nt], 0, 0, 0);
      }
    }
  }

  // epilogue
  int qrow[4]; bool msk[4]; float inv[4];
#pragma unroll
  for (int r = 0; r < 4; ++r) {
    qrow[r] = rowbase + q4 * 4 + r;
    msk[r] = (mask[b * TT + qrow[r]] == 0);
    inv[r] = 1.f / l_i[r];
  }
#pragma unroll
  for (int nt = 0; nt < 4; ++nt) {
    int d = nt * 16 + c;
    float mv = meanv[bh * HD + d];
#pragma unroll
    for (int r = 0; r < 4; ++r) {
      float val = msk[r] ? mv : o[nt][r] * inv[r];
      outb[((size_t)(b * TT + qrow[r])) * CC + h * HD + d] = f2bf(val);
    }
  }
}

// ---------------- launcher ----------------
extern "C" void kernel_launch(void* const* d_in, const int* in_sizes, int n_in,
                              void* d_out, int out_size, void* d_ws, size_t ws_size,
                              hipStream_t stream)
{
  (void)in_sizes; (void)n_in; (void)out_size; (void)ws_size;
  const float* x     = (const float*)d_in[0];
  const int*   mask  = (const int*)d_in[1];
  const float* Wattn = (const float*)d_in[2];
  const float* battn = (const float*)d_in[3];
  const float* Wproj = (const float*)d_in[4];
  const float* bproj = (const float*)d_in[5];
  float* out = (float*)d_out;

  char* ws = (char*)d_ws;
  size_t off = 0;
  auto alloc = [&](size_t bytes) -> void* {
    void* p = ws + off;
    off += (bytes + 255) & ~(size_t)255;
    return p;
  };
  u16* WtA  = (u16*)alloc((size_t)NQKV * KD * 2);
  u16* WtP  = (u16*)alloc((size_t)CC * CC * 2);
  u16* xb   = (u16*)alloc((size_t)MROWS * CC * 2);
  u16* qbuf = (u16*)alloc((size_t)MROWS * CC * 2);
  u16* kbuf = (u16*)alloc((size_t)MROWS * CC * 2);
  u16* vbuf = (u16*)alloc((size_t)MROWS * CC * 2);
  u16* vtb  = (u16*)alloc((size_t)MROWS * CC * 2);   // [bh][d][t]
  u16* abuf = (u16*)alloc((size_t)MROWS * CC * 2);
  float* mv = (float*)alloc((size_t)BH * HD * 4);

  int nx = MROWS * CC;
  convert_f32_bf16<<<nx / (256 * 4), 256, 0, stream>>>(x, xb, nx);
  transpose_f32_bf16<<<(NQKV/32)*(KD/32), 256, 0, stream>>>(Wattn, WtA, KD, NQKV);
  transpose_f32_bf16<<<(CC/32)*(CC/32),   256, 0, stream>>>(Wproj, WtP, CC, CC);

  gemm_bt<<<(MROWS/64)*(NQKV/64), 256, 0, stream>>>(
      xb, WtA, battn, nullptr, qbuf, kbuf, vbuf, MROWS, NQKV, 0);

  transpose_v<<<BH * (TT/64), 256, 0, stream>>>(vbuf, vtb);
  vmean_kernel<<<BH, 64, 0, stream>>>(vbuf, mv);

  attn_kernel<<<BH * (TT/64), 256, 0, stream>>>(qbuf, kbuf, vtb, mask, mv, abuf);

  gemm_bt<<<(MROWS/64)*(CC/64), 256, 0, stream>>>(
      abuf, WtP, bproj, out, nullptr, nullptr, nullptr, MROWS, CC, 1);
}

// Round 5
// 271.739 us; speedup vs baseline: 2.8581x; 1.1384x over previous
//
#include <hip/hip_runtime.h>

#define BQ 8
#define TT 1024
#define CC 768
#define NH 12
#define HD 64
#define BH (BQ*NH)      // 96
#define MROWS (BQ*TT)   // 8192
#define NQKV (3*CC)     // 2304
#define KD CC           // 768

typedef unsigned short u16;
typedef __attribute__((ext_vector_type(4))) short short4v;
typedef __attribute__((ext_vector_type(8))) short short8v;
typedef __attribute__((ext_vector_type(4))) float floatx4;

__device__ __forceinline__ float bf2f(u16 u) {
  union { unsigned int i; float f; } c; c.i = ((unsigned int)u) << 16; return c.f;
}
__device__ __forceinline__ u16 f2bf(float f) {
  union { float f; unsigned int i; } c; c.f = f;
  unsigned int i = c.i;
  return (u16)((i + 0x7FFFu + ((i >> 16) & 1u)) >> 16);  // RNE
}
__device__ __forceinline__ float fast_exp2(float x) {
  return __builtin_amdgcn_exp2f(x);   // v_exp_f32 (base-2)
}

// ---------------- elementwise f32 -> bf16 ----------------
__global__ __launch_bounds__(256) void convert_f32_bf16(
    const float* __restrict__ in, u16* __restrict__ out, int n)
{
  int i = (blockIdx.x * 256 + threadIdx.x) * 4;
  if (i >= n) return;
  floatx4 v = *(const floatx4*)(in + i);
  short4v o;
  o[0] = (short)f2bf(v[0]); o[1] = (short)f2bf(v[1]);
  o[2] = (short)f2bf(v[2]); o[3] = (short)f2bf(v[3]);
  *(short4v*)(out + i) = o;
}

// ---------- transpose f32 [R,Cc] -> bf16 [Cc,R] ----------
__global__ __launch_bounds__(256) void transpose_f32_bf16(
    const float* __restrict__ in, u16* __restrict__ out, int R, int Cc)
{
  __shared__ float tile[32][33];
  int ct = Cc >> 5;
  int bx = blockIdx.x % ct;
  int by = blockIdx.x / ct;
  int tx = threadIdx.x & 31;
  int ty = threadIdx.x >> 5;    // 0..7
  int c0 = bx << 5, r0 = by << 5;
#pragma unroll
  for (int s = 0; s < 4; ++s)
    tile[ty + s*8][tx] = in[(size_t)(r0 + ty + s*8) * Cc + c0 + tx];
  __syncthreads();
#pragma unroll
  for (int s = 0; s < 4; ++s)
    out[(size_t)(c0 + ty + s*8) * R + r0 + tx] = f2bf(tile[tx][ty + s*8]);
}

// ---------------- GEMM: C[M,N] = A[M,K] * Bt[N,K]^T + bias (f32) ----------------
#define LDK 40

__global__ __launch_bounds__(256) void gemm_bt(
    const u16* __restrict__ A, const u16* __restrict__ Bt,
    const float* __restrict__ bias,
    float* __restrict__ out,
    u16* __restrict__ qo, u16* __restrict__ ko, u16* __restrict__ vo,
    int M, int N, int mode)
{
  const int K = KD;
  __shared__ u16 As[64 * LDK];
  __shared__ u16 Bs[64 * LDK];
  int tid = threadIdx.x;
  int lane = tid & 63;
  int wave = tid >> 6;
  int wr = (wave >> 1) << 5;
  int wc = (wave & 1) << 5;
  int mtiles = M >> 6;
  int mt = blockIdx.x % mtiles;
  int nt = blockIdx.x / mtiles;
  int m0 = mt << 6, n0 = nt << 6;

  int srow = tid >> 2;
  int scol = (tid & 3) << 3;
  const u16* ag = A + (size_t)(m0 + srow) * K + scol;
  const u16* bg = Bt + (size_t)(n0 + srow) * K + scol;
  u16* asw = &As[srow * LDK + scol];
  u16* bsw = &Bs[srow * LDK + scol];

  int lr = lane & 15;
  int lq = lane >> 4;
  const u16* ar0 = &As[(wr + lr) * LDK + lq * 4];
  const u16* ar1 = ar0 + (LDK << 4);
  const u16* br0 = &Bs[(wc + lr) * LDK + lq * 4];
  const u16* br1 = br0 + (LDK << 4);

  floatx4 z = {0.f, 0.f, 0.f, 0.f};
  floatx4 acc00 = z, acc01 = z, acc10 = z, acc11 = z;

  for (int kt = 0; kt < K; kt += 32) {
    *(short8v*)asw = *(const short8v*)(ag + kt);
    *(short8v*)bsw = *(const short8v*)(bg + kt);
    __syncthreads();
    short4v a0l = *(const short4v*)(ar0);
    short4v a0h = *(const short4v*)(ar0 + 16);
    short4v a1l = *(const short4v*)(ar1);
    short4v a1h = *(const short4v*)(ar1 + 16);
    short4v b0l = *(const short4v*)(br0);
    short4v b0h = *(const short4v*)(br0 + 16);
    short4v b1l = *(const short4v*)(br1);
    short4v b1h = *(const short4v*)(br1 + 16);
    acc00 = __builtin_amdgcn_mfma_f32_16x16x16bf16_1k(a0l, b0l, acc00, 0, 0, 0);
    acc01 = __builtin_amdgcn_mfma_f32_16x16x16bf16_1k(a0l, b1l, acc01, 0, 0, 0);
    acc10 = __builtin_amdgcn_mfma_f32_16x16x16bf16_1k(a1l, b0l, acc10, 0, 0, 0);
    acc11 = __builtin_amdgcn_mfma_f32_16x16x16bf16_1k(a1l, b1l, acc11, 0, 0, 0);
    acc00 = __builtin_amdgcn_mfma_f32_16x16x16bf16_1k(a0h, b0h, acc00, 0, 0, 0);
    acc01 = __builtin_amdgcn_mfma_f32_16x16x16bf16_1k(a0h, b1h, acc01, 0, 0, 0);
    acc10 = __builtin_amdgcn_mfma_f32_16x16x16bf16_1k(a1h, b0h, acc10, 0, 0, 0);
    acc11 = __builtin_amdgcn_mfma_f32_16x16x16bf16_1k(a1h, b1h, acc11, 0, 0, 0);
    __syncthreads();
  }

  floatx4 accs[2][2] = {{acc00, acc01}, {acc10, acc11}};
#pragma unroll
  for (int i = 0; i < 2; ++i) {
#pragma unroll
    for (int j = 0; j < 2; ++j) {
      int nn = n0 + wc + j * 16 + lr;
      float bv = bias[nn];
#pragma unroll
      for (int r = 0; r < 4; ++r) {
        int mm = m0 + wr + i * 16 + lq * 4 + r;
        float val = accs[i][j][r] + bv;
        if (mode == 0) {
          int bb = mm >> 10, tt = mm & 1023;
          int which = nn / CC;
          int rem = nn - which * CC;
          int hh = rem >> 6, dd = rem & 63;
          size_t idx = (((size_t)(bb * NH + hh)) * TT + tt) * HD + dd;
          u16* dst = (which == 0) ? qo : ((which == 1) ? ko : vo);
          dst[idx] = f2bf(val);
        } else {
          out[(size_t)mm * N + nn] = val;
        }
      }
    }
  }
}

// ---------------- V transpose: vbuf [bh][t][d] -> vtb [bh][d][t] ----------------
__global__ __launch_bounds__(256) void transpose_v(
    const u16* __restrict__ vb, u16* __restrict__ vt)
{
  __shared__ u16 tile[64][72];
  int tid = threadIdx.x;
  int tt0 = (blockIdx.x & 15) << 6;
  int bh = blockIdx.x >> 4;
  {
    int trow = tid >> 2;
    int dchunk = (tid & 3) << 4;
    const u16* src = vb + (((size_t)bh * TT + tt0 + trow) * HD) + dchunk;
    *(short8v*)&tile[trow][dchunk]     = *(const short8v*)src;
    *(short8v*)&tile[trow][dchunk + 8] = *(const short8v*)(src + 8);
  }
  __syncthreads();
  {
    int drow = tid >> 2;
    int tchunk = (tid & 3) << 4;
    short8v a, bv;
#pragma unroll
    for (int j = 0; j < 8; ++j) {
      a[j]  = (short)tile[tchunk + j][drow];
      bv[j] = (short)tile[tchunk + 8 + j][drow];
    }
    u16* dst = vt + ((size_t)bh * HD + drow) * TT + tt0 + tchunk;
    *(short8v*)dst       = a;
    *(short8v*)(dst + 8) = bv;
  }
}

// ---------------- mean of V over T, per (b,h,d) ----------------
__global__ __launch_bounds__(64) void vmean_kernel(
    const u16* __restrict__ vb, float* __restrict__ mv)
{
  int bh = blockIdx.x;
  int d = threadIdx.x;
  const u16* p = vb + (size_t)bh * TT * HD + d;
  float s0 = 0.f, s1 = 0.f, s2 = 0.f, s3 = 0.f;
  for (int t = 0; t < TT; t += 4) {
    s0 += bf2f(p[(size_t)(t + 0) * HD]);
    s1 += bf2f(p[(size_t)(t + 1) * HD]);
    s2 += bf2f(p[(size_t)(t + 2) * HD]);
    s3 += bf2f(p[(size_t)(t + 3) * HD]);
  }
  mv[bh * HD + d] = (s0 + s1 + s2 + s3) * (1.0f / 1024.0f);
}

// ---------------- MFMA flash attention (balanced pairs + pipelined staging) ----------------
// Block handles q-tiles {p, 15-p}: every block does exactly 17 tile-iterations.
// Layouts (verified): A/B frag [idx=lane&15][k=quad*8+j]; C/D col=lane&15, row=quad*4+reg.
#define LDW 72
#define SCL 0.18033688f   // (1/sqrt(64)) * log2(e); softmax done in exp2 domain

__global__ __launch_bounds__(256) void attn_kernel(
    const u16* __restrict__ qb, const u16* __restrict__ kb,
    const u16* __restrict__ vtb, const int* __restrict__ mask,
    const float* __restrict__ meanv, u16* __restrict__ outb)
{
  __shared__ u16 Ks[64 * LDW];       // K tile [key][d]
  __shared__ u16 Vs[64 * LDW];       // V^T tile [d][key]
  __shared__ u16 Ps[4][16 * LDW];    // per-wave P [row][key]

  int tid = threadIdx.x;
  int lane = tid & 63;
  int w = tid >> 6;
  int c = lane & 15;     // fragment index (col)
  int q4 = lane >> 4;    // quad 0..3

  int pair = blockIdx.x & 7;
  int bh = blockIdx.x >> 3;
  int b = bh / NH;
  int h = bh - b * NH;

  // staging addresses: thread stages 32 B of a K row and 32 B of a Vt row
  int srow = tid >> 2;
  int schunk = (tid & 3) << 4;
  const u16* kgp = kb + ((size_t)bh * TT + srow) * HD + schunk;
  const u16* vgp = vtb + ((size_t)bh * HD + srow) * TT + schunk;
  u16* ksw = &Ks[srow * LDW + schunk];
  u16* vsw = &Vs[srow * LDW + schunk];
  u16* pw = &Ps[w][0];

#pragma unroll 1
  for (int phase = 0; phase < 2; ++phase) {
    int qt = phase ? (15 - pair) : pair;
    int rowbase = (qt << 6) + (w << 4);

    // Q A-fragments for this q-tile
    short8v qfrag[2];
    {
      const u16* qp = qb + ((size_t)bh * TT + rowbase + c) * HD + q4 * 8;
      qfrag[0] = *(const short8v*)qp;
      qfrag[1] = *(const short8v*)(qp + 32);
    }

    floatx4 o[4];
#pragma unroll
    for (int i = 0; i < 4; ++i) o[i] = (floatx4){0.f, 0.f, 0.f, 0.f};
    float m_i[4], l_i[4];
#pragma unroll
    for (int r = 0; r < 4; ++r) { m_i[r] = -INFINITY; l_i[r] = 0.f; }

    // prefetch tile kt=0 into registers
    short8v kr0, kr1, vr0, vr1;
    kr0 = *(const short8v*)kgp;
    kr1 = *(const short8v*)(kgp + 8);
    vr0 = *(const short8v*)vgp;
    vr1 = *(const short8v*)(vgp + 8);

#pragma unroll 1
    for (int kt = 0; kt <= qt; ++kt) {
      __syncthreads();   // previous tile's LDS reads complete
      *(short8v*)ksw = kr0; *(short8v*)(ksw + 8) = kr1;
      *(short8v*)vsw = vr0; *(short8v*)(vsw + 8) = vr1;
      __syncthreads();

      if (kt < qt) {   // prefetch next tile; waitcnt lands at next LDS store
        const u16* kp = kgp + ((size_t)(kt + 1) << 6) * HD;
        const u16* vp = vgp + ((kt + 1) << 6);
        kr0 = *(const short8v*)kp;
        kr1 = *(const short8v*)(kp + 8);
        vr0 = *(const short8v*)vp;
        vr1 = *(const short8v*)(vp + 8);
      }

      // QK^T: s[nt] = S[row][key=nt*16+c]
      floatx4 s[4];
#pragma unroll
      for (int nt = 0; nt < 4; ++nt) s[nt] = (floatx4){0.f, 0.f, 0.f, 0.f};
#pragma unroll
      for (int kc = 0; kc < 2; ++kc) {
#pragma unroll
        for (int nt = 0; nt < 4; ++nt) {
          short8v kf = *(const short8v*)&Ks[(nt * 16 + c) * LDW + kc * 32 + q4 * 8];
          s[nt] = __builtin_amdgcn_mfma_f32_16x16x32_bf16(qfrag[kc], kf, s[nt], 0, 0, 0);
        }
      }

      // scale into exp2 domain + causal mask (diag tile only)
      if (kt == qt) {
#pragma unroll
        for (int nt = 0; nt < 4; ++nt)
#pragma unroll
          for (int r = 0; r < 4; ++r) {
            float sv = s[nt][r] * SCL;
            if (nt * 16 + c > (w << 4) + q4 * 4 + r) sv = -INFINITY;
            s[nt][r] = sv;
          }
      } else {
#pragma unroll
        for (int nt = 0; nt < 4; ++nt)
#pragma unroll
          for (int r = 0; r < 4; ++r) s[nt][r] *= SCL;
      }

      // row max over 64 keys
      float mt[4];
#pragma unroll
      for (int r = 0; r < 4; ++r)
        mt[r] = fmaxf(fmaxf(s[0][r], s[1][r]), fmaxf(s[2][r], s[3][r]));
#pragma unroll
      for (int r = 0; r < 4; ++r) {
        mt[r] = fmaxf(mt[r], __shfl_xor(mt[r], 1));
        mt[r] = fmaxf(mt[r], __shfl_xor(mt[r], 2));
        mt[r] = fmaxf(mt[r], __shfl_xor(mt[r], 4));
        mt[r] = fmaxf(mt[r], __shfl_xor(mt[r], 8));
      }

      float al[4];
#pragma unroll
      for (int r = 0; r < 4; ++r) {
        float mn = fmaxf(m_i[r], mt[r]);
        al[r] = fast_exp2(m_i[r] - mn);
        m_i[r] = mn;
      }

      float ps[4] = {0.f, 0.f, 0.f, 0.f};
#pragma unroll
      for (int nt = 0; nt < 4; ++nt)
#pragma unroll
        for (int r = 0; r < 4; ++r) {
          float p = fast_exp2(s[nt][r] - m_i[r]);
          ps[r] += p;
          pw[(q4 * 4 + r) * LDW + nt * 16 + c] = f2bf(p);
        }
#pragma unroll
      for (int r = 0; r < 4; ++r) {
        ps[r] += __shfl_xor(ps[r], 1);
        ps[r] += __shfl_xor(ps[r], 2);
        ps[r] += __shfl_xor(ps[r], 4);
        ps[r] += __shfl_xor(ps[r], 8);
        l_i[r] = l_i[r] * al[r] + ps[r];
      }
#pragma unroll
      for (int nt = 0; nt < 4; ++nt)
#pragma unroll
        for (int r = 0; r < 4; ++r) o[nt][r] *= al[r];

      // PV: O[row][d=nt*16+c] += P[row][key] * Vt[d][key]  (P wave-private)
#pragma unroll
      for (int kc = 0; kc < 2; ++kc) {
        short8v pf = *(const short8v*)&pw[c * LDW + kc * 32 + q4 * 8];
#pragma unroll
        for (int nt = 0; nt < 4; ++nt) {
          short8v vf = *(const short8v*)&Vs[(nt * 16 + c) * LDW + kc * 32 + q4 * 8];
          o[nt] = __builtin_amdgcn_mfma_f32_16x16x32_bf16(pf, vf, o[nt], 0, 0, 0);
        }
      }
    }

    // epilogue for this q-tile
    int qrow[4]; bool msk[4]; float inv[4];
#pragma unroll
    for (int r = 0; r < 4; ++r) {
      qrow[r] = rowbase + q4 * 4 + r;
      msk[r] = (mask[b * TT + qrow[r]] == 0);
      inv[r] = 1.f / l_i[r];
    }
#pragma unroll
    for (int nt = 0; nt < 4; ++nt) {
      int d = nt * 16 + c;
      float mv = meanv[bh * HD + d];
#pragma unroll
      for (int r = 0; r < 4; ++r) {
        float val = msk[r] ? mv : o[nt][r] * inv[r];
        outb[((size_t)(b * TT + qrow[r])) * CC + h * HD + d] = f2bf(val);
      }
    }
  }
}

// ---------------- launcher ----------------
extern "C" void kernel_launch(void* const* d_in, const int* in_sizes, int n_in,
                              void* d_out, int out_size, void* d_ws, size_t ws_size,
                              hipStream_t stream)
{
  (void)in_sizes; (void)n_in; (void)out_size; (void)ws_size;
  const float* x     = (const float*)d_in[0];
  const int*   mask  = (const int*)d_in[1];
  const float* Wattn = (const float*)d_in[2];
  const float* battn = (const float*)d_in[3];
  const float* Wproj = (const float*)d_in[4];
  const float* bproj = (const float*)d_in[5];
  float* out = (float*)d_out;

  char* ws = (char*)d_ws;
  size_t off = 0;
  auto alloc = [&](size_t bytes) -> void* {
    void* p = ws + off;
    off += (bytes + 255) & ~(size_t)255;
    return p;
  };
  u16* WtA  = (u16*)alloc((size_t)NQKV * KD * 2);
  u16* WtP  = (u16*)alloc((size_t)CC * CC * 2);
  u16* xb   = (u16*)alloc((size_t)MROWS * CC * 2);
  u16* qbuf = (u16*)alloc((size_t)MROWS * CC * 2);
  u16* kbuf = (u16*)alloc((size_t)MROWS * CC * 2);
  u16* vbuf = (u16*)alloc((size_t)MROWS * CC * 2);
  u16* vtb  = (u16*)alloc((size_t)MROWS * CC * 2);   // [bh][d][t]
  u16* abuf = (u16*)alloc((size_t)MROWS * CC * 2);
  float* mv = (float*)alloc((size_t)BH * HD * 4);

  int nx = MROWS * CC;
  convert_f32_bf16<<<nx / (256 * 4), 256, 0, stream>>>(x, xb, nx);
  transpose_f32_bf16<<<(NQKV/32)*(KD/32), 256, 0, stream>>>(Wattn, WtA, KD, NQKV);
  transpose_f32_bf16<<<(CC/32)*(CC/32),   256, 0, stream>>>(Wproj, WtP, CC, CC);

  gemm_bt<<<(MROWS/64)*(NQKV/64), 256, 0, stream>>>(
      xb, WtA, battn, nullptr, qbuf, kbuf, vbuf, MROWS, NQKV, 0);

  transpose_v<<<BH * (TT/64), 256, 0, stream>>>(vbuf, vtb);
  vmean_kernel<<<BH, 64, 0, stream>>>(vbuf, mv);

  attn_kernel<<<BH * 8, 256, 0, stream>>>(qbuf, kbuf, vtb, mask, mv, abuf);

  gemm_bt<<<(MROWS/64)*(CC/64), 256, 0, stream>>>(
      abuf, WtP, bproj, out, nullptr, nullptr, nullptr, MROWS, CC, 1);
}

// Round 6
// 249.629 us; speedup vs baseline: 3.1113x; 1.0886x over previous
//
#include <hip/hip_runtime.h>

#define BQ 8
#define TT 1024
#define CC 768
#define NH 12
#define HD 64
#define BH (BQ*NH)      // 96
#define MROWS (BQ*TT)   // 8192
#define NQKV (3*CC)     // 2304
#define KD CC           // 768

typedef unsigned short u16;
typedef __attribute__((ext_vector_type(4))) short short4v;
typedef __attribute__((ext_vector_type(8))) short short8v;
typedef __attribute__((ext_vector_type(4))) float floatx4;
typedef __attribute__((address_space(1))) const unsigned int gu32;
typedef __attribute__((address_space(3))) unsigned int lu32;

__device__ __forceinline__ float bf2f(u16 u) {
  union { unsigned int i; float f; } c; c.i = ((unsigned int)u) << 16; return c.f;
}
__device__ __forceinline__ u16 f2bf(float f) {
  union { float f; unsigned int i; } c; c.f = f;
  unsigned int i = c.i;
  return (u16)((i + 0x7FFFu + ((i >> 16) & 1u)) >> 16);  // RNE
}
__device__ __forceinline__ float fast_exp2(float x) {
  return __builtin_amdgcn_exp2f(x);   // v_exp_f32 (base-2)
}
// async global->LDS, 16 B per lane; LDS dest = wave-uniform base + lane*16
__device__ __forceinline__ void async_ld16(const u16* g, u16* l) {
  __builtin_amdgcn_global_load_lds((gu32*)g, (lu32*)l, 16, 0, 0);
}

// ---------------- elementwise f32 -> bf16 ----------------
__global__ __launch_bounds__(256) void convert_f32_bf16(
    const float* __restrict__ in, u16* __restrict__ out, int n)
{
  int i = (blockIdx.x * 256 + threadIdx.x) * 4;
  if (i >= n) return;
  floatx4 v = *(const floatx4*)(in + i);
  short4v o;
  o[0] = (short)f2bf(v[0]); o[1] = (short)f2bf(v[1]);
  o[2] = (short)f2bf(v[2]); o[3] = (short)f2bf(v[3]);
  *(short4v*)(out + i) = o;
}

// ---------- transpose f32 [R,Cc] -> bf16 [Cc,R] ----------
__global__ __launch_bounds__(256) void transpose_f32_bf16(
    const float* __restrict__ in, u16* __restrict__ out, int R, int Cc)
{
  __shared__ float tile[32][33];
  int ct = Cc >> 5;
  int bx = blockIdx.x % ct;
  int by = blockIdx.x / ct;
  int tx = threadIdx.x & 31;
  int ty = threadIdx.x >> 5;    // 0..7
  int c0 = bx << 5, r0 = by << 5;
#pragma unroll
  for (int s = 0; s < 4; ++s)
    tile[ty + s*8][tx] = in[(size_t)(r0 + ty + s*8) * Cc + c0 + tx];
  __syncthreads();
#pragma unroll
  for (int s = 0; s < 4; ++s)
    out[(size_t)(c0 + ty + s*8) * R + r0 + tx] = f2bf(tile[tx][ty + s*8]);
}

// ------- GEMM (m97 structure): 128x128 tile, BK=32, global_load_lds staging -------
// C[M,N] = A[M,K] * Bt[N,K]^T + bias. mode 0: scatter q/k/v bf16; mode 1: f32 out.
__global__ __launch_bounds__(256) void gemm_bt(
    const u16* __restrict__ A, const u16* __restrict__ Bt,
    const float* __restrict__ bias,
    float* __restrict__ out,
    u16* __restrict__ qo, u16* __restrict__ ko, u16* __restrict__ vo,
    int M, int N, int mode)
{
  __shared__ u16 As[128 * 32];   // [row][k], UNPADDED (global_load_lds lane order)
  __shared__ u16 Bs[128 * 32];

  int tid = threadIdx.x;
  int lane = tid & 63;
  int w = tid >> 6;
  int c = lane & 15;     // fragment col
  int q4 = lane >> 4;    // quad

  int mtiles = M >> 7;
  int mt = blockIdx.x % mtiles;
  int nt = blockIdx.x / mtiles;
  int m0 = mt << 7, n0 = nt << 7;

  int wr = (w >> 1) << 6;   // wave quadrant: 0/64
  int wc = (w & 1) << 6;

  // staging: wave w stages A rows [w*32, w*32+32) and B rows likewise (2 insts each)
  int srow = lane >> 2;          // 0..15
  int sk = (lane & 3) << 3;      // chunk of 8 shorts (16 B)
  const u16* ag = A + (size_t)(m0 + w * 32 + srow) * KD + sk;
  const u16* bg = Bt + (size_t)(n0 + w * 32 + srow) * KD + sk;
  u16* asl = &As[(w * 32) * 32];   // wave-uniform LDS bases
  u16* bsl = &Bs[(w * 32) * 32];

  floatx4 acc[4][4];
#pragma unroll
  for (int mi = 0; mi < 4; ++mi)
#pragma unroll
    for (int ni = 0; ni < 4; ++ni) acc[mi][ni] = (floatx4){0.f, 0.f, 0.f, 0.f};

#pragma unroll 1
  for (int kt = 0; kt < KD; kt += 32) {
    async_ld16(ag + kt,            asl);
    async_ld16(ag + kt + 16 * KD,  asl + 16 * 32);
    async_ld16(bg + kt,            bsl);
    async_ld16(bg + kt + 16 * KD,  bsl + 16 * 32);
    __syncthreads();   // drains vmcnt(0): LDS tiles complete

    short8v af[4], bf[4];
#pragma unroll
    for (int mi = 0; mi < 4; ++mi)
      af[mi] = *(const short8v*)&As[(wr + mi * 16 + c) * 32 + q4 * 8];
#pragma unroll
    for (int ni = 0; ni < 4; ++ni)
      bf[ni] = *(const short8v*)&Bs[(wc + ni * 16 + c) * 32 + q4 * 8];
#pragma unroll
    for (int mi = 0; mi < 4; ++mi)
#pragma unroll
      for (int ni = 0; ni < 4; ++ni)
        acc[mi][ni] = __builtin_amdgcn_mfma_f32_16x16x32_bf16(af[mi], bf[ni], acc[mi][ni], 0, 0, 0);
    __syncthreads();   // all reads done before next stage overwrites
  }

  // epilogue
  if (mode == 0) {
    int which = (n0 + wc) / CC;            // wave-uniform: 64-col span within one of q/k/v
    int nbase = (n0 + wc) - which * CC;
    u16* dst0 = (which == 0) ? qo : ((which == 1) ? ko : vo);
#pragma unroll
    for (int ni = 0; ni < 4; ++ni) {
      int nn = nbase + ni * 16 + c;        // 0..767 within q/k/v
      int hh = nn >> 6, dd = nn & 63;
      float bv = bias[which * CC + nn];
#pragma unroll
      for (int mi = 0; mi < 4; ++mi) {
#pragma unroll
        for (int r = 0; r < 4; ++r) {
          int mm = m0 + wr + mi * 16 + q4 * 4 + r;
          int bb = mm >> 10, tt = mm & 1023;
          size_t idx = (((size_t)(bb * NH + hh)) * TT + tt) * HD + dd;
          dst0[idx] = f2bf(acc[mi][ni][r] + bv);
        }
      }
    }
  } else {
#pragma unroll
    for (int ni = 0; ni < 4; ++ni) {
      int nn = n0 + wc + ni * 16 + c;
      float bv = bias[nn];
#pragma unroll
      for (int mi = 0; mi < 4; ++mi) {
#pragma unroll
        for (int r = 0; r < 4; ++r) {
          int mm = m0 + wr + mi * 16 + q4 * 4 + r;
          out[(size_t)mm * N + nn] = acc[mi][ni][r] + bv;
        }
      }
    }
  }
}

// ---------------- V transpose: vbuf [bh][t][d] -> vtb [bh][d][t] ----------------
__global__ __launch_bounds__(256) void transpose_v(
    const u16* __restrict__ vb, u16* __restrict__ vt)
{
  __shared__ u16 tile[64][72];
  int tid = threadIdx.x;
  int tt0 = (blockIdx.x & 15) << 6;
  int bh = blockIdx.x >> 4;
  {
    int trow = tid >> 2;
    int dchunk = (tid & 3) << 4;
    const u16* src = vb + (((size_t)bh * TT + tt0 + trow) * HD) + dchunk;
    *(short8v*)&tile[trow][dchunk]     = *(const short8v*)src;
    *(short8v*)&tile[trow][dchunk + 8] = *(const short8v*)(src + 8);
  }
  __syncthreads();
  {
    int drow = tid >> 2;
    int tchunk = (tid & 3) << 4;
    short8v a, bv;
#pragma unroll
    for (int j = 0; j < 8; ++j) {
      a[j]  = (short)tile[tchunk + j][drow];
      bv[j] = (short)tile[tchunk + 8 + j][drow];
    }
    u16* dst = vt + ((size_t)bh * HD + drow) * TT + tt0 + tchunk;
    *(short8v*)dst       = a;
    *(short8v*)(dst + 8) = bv;
  }
}

// ---------------- mean of V over T, per (b,h,d) ----------------
__global__ __launch_bounds__(64) void vmean_kernel(
    const u16* __restrict__ vb, float* __restrict__ mv)
{
  int bh = blockIdx.x;
  int d = threadIdx.x;
  const u16* p = vb + (size_t)bh * TT * HD + d;
  float s0 = 0.f, s1 = 0.f, s2 = 0.f, s3 = 0.f;
  for (int t = 0; t < TT; t += 4) {
    s0 += bf2f(p[(size_t)(t + 0) * HD]);
    s1 += bf2f(p[(size_t)(t + 1) * HD]);
    s2 += bf2f(p[(size_t)(t + 2) * HD]);
    s3 += bf2f(p[(size_t)(t + 3) * HD]);
  }
  mv[bh * HD + d] = (s0 + s1 + s2 + s3) * (1.0f / 1024.0f);
}

// ---------------- MFMA flash attention (balanced pairs + pipelined staging) ----------------
#define LDW 72
#define SCL 0.18033688f   // (1/sqrt(64)) * log2(e); softmax in exp2 domain

__global__ __launch_bounds__(256) void attn_kernel(
    const u16* __restrict__ qb, const u16* __restrict__ kb,
    const u16* __restrict__ vtb, const int* __restrict__ mask,
    const float* __restrict__ meanv, u16* __restrict__ outb)
{
  __shared__ u16 Ks[64 * LDW];       // K tile [key][d]
  __shared__ u16 Vs[64 * LDW];       // V^T tile [d][key]
  __shared__ u16 Ps[4][16 * LDW];    // per-wave P [row][key]

  int tid = threadIdx.x;
  int lane = tid & 63;
  int w = tid >> 6;
  int c = lane & 15;
  int q4 = lane >> 4;

  int pair = blockIdx.x & 7;
  int bh = blockIdx.x >> 3;
  int b = bh / NH;
  int h = bh - b * NH;

  int srow = tid >> 2;
  int schunk = (tid & 3) << 4;
  const u16* kgp = kb + ((size_t)bh * TT + srow) * HD + schunk;
  const u16* vgp = vtb + ((size_t)bh * HD + srow) * TT + schunk;
  u16* ksw = &Ks[srow * LDW + schunk];
  u16* vsw = &Vs[srow * LDW + schunk];
  u16* pw = &Ps[w][0];

#pragma unroll 1
  for (int phase = 0; phase < 2; ++phase) {
    int qt = phase ? (15 - pair) : pair;
    int rowbase = (qt << 6) + (w << 4);

    short8v qfrag[2];
    {
      const u16* qp = qb + ((size_t)bh * TT + rowbase + c) * HD + q4 * 8;
      qfrag[0] = *(const short8v*)qp;
      qfrag[1] = *(const short8v*)(qp + 32);
    }

    floatx4 o[4];
#pragma unroll
    for (int i = 0; i < 4; ++i) o[i] = (floatx4){0.f, 0.f, 0.f, 0.f};
    float m_i[4], l_i[4];
#pragma unroll
    for (int r = 0; r < 4; ++r) { m_i[r] = -INFINITY; l_i[r] = 0.f; }

    short8v kr0, kr1, vr0, vr1;
    kr0 = *(const short8v*)kgp;
    kr1 = *(const short8v*)(kgp + 8);
    vr0 = *(const short8v*)vgp;
    vr1 = *(const short8v*)(vgp + 8);

#pragma unroll 1
    for (int kt = 0; kt <= qt; ++kt) {
      __syncthreads();
      *(short8v*)ksw = kr0; *(short8v*)(ksw + 8) = kr1;
      *(short8v*)vsw = vr0; *(short8v*)(vsw + 8) = vr1;
      __syncthreads();

      if (kt < qt) {
        const u16* kp = kgp + ((size_t)(kt + 1) << 6) * HD;
        const u16* vp = vgp + ((kt + 1) << 6);
        kr0 = *(const short8v*)kp;
        kr1 = *(const short8v*)(kp + 8);
        vr0 = *(const short8v*)vp;
        vr1 = *(const short8v*)(vp + 8);
      }

      floatx4 s[4];
#pragma unroll
      for (int nt = 0; nt < 4; ++nt) s[nt] = (floatx4){0.f, 0.f, 0.f, 0.f};
#pragma unroll
      for (int kc = 0; kc < 2; ++kc) {
#pragma unroll
        for (int nt = 0; nt < 4; ++nt) {
          short8v kf = *(const short8v*)&Ks[(nt * 16 + c) * LDW + kc * 32 + q4 * 8];
          s[nt] = __builtin_amdgcn_mfma_f32_16x16x32_bf16(qfrag[kc], kf, s[nt], 0, 0, 0);
        }
      }

      if (kt == qt) {
#pragma unroll
        for (int nt = 0; nt < 4; ++nt)
#pragma unroll
          for (int r = 0; r < 4; ++r) {
            float sv = s[nt][r] * SCL;
            if (nt * 16 + c > (w << 4) + q4 * 4 + r) sv = -INFINITY;
            s[nt][r] = sv;
          }
      } else {
#pragma unroll
        for (int nt = 0; nt < 4; ++nt)
#pragma unroll
          for (int r = 0; r < 4; ++r) s[nt][r] *= SCL;
      }

      float mt[4];
#pragma unroll
      for (int r = 0; r < 4; ++r)
        mt[r] = fmaxf(fmaxf(s[0][r], s[1][r]), fmaxf(s[2][r], s[3][r]));
#pragma unroll
      for (int r = 0; r < 4; ++r) {
        mt[r] = fmaxf(mt[r], __shfl_xor(mt[r], 1));
        mt[r] = fmaxf(mt[r], __shfl_xor(mt[r], 2));
        mt[r] = fmaxf(mt[r], __shfl_xor(mt[r], 4));
        mt[r] = fmaxf(mt[r], __shfl_xor(mt[r], 8));
      }

      float al[4];
#pragma unroll
      for (int r = 0; r < 4; ++r) {
        float mn = fmaxf(m_i[r], mt[r]);
        al[r] = fast_exp2(m_i[r] - mn);
        m_i[r] = mn;
      }

      float ps[4] = {0.f, 0.f, 0.f, 0.f};
#pragma unroll
      for (int nt = 0; nt < 4; ++nt)
#pragma unroll
        for (int r = 0; r < 4; ++r) {
          float p = fast_exp2(s[nt][r] - m_i[r]);
          ps[r] += p;
          pw[(q4 * 4 + r) * LDW + nt * 16 + c] = f2bf(p);
        }
#pragma unroll
      for (int r = 0; r < 4; ++r) {
        ps[r] += __shfl_xor(ps[r], 1);
        ps[r] += __shfl_xor(ps[r], 2);
        ps[r] += __shfl_xor(ps[r], 4);
        ps[r] += __shfl_xor(ps[r], 8);
        l_i[r] = l_i[r] * al[r] + ps[r];
      }
#pragma unroll
      for (int nt = 0; nt < 4; ++nt)
#pragma unroll
        for (int r = 0; r < 4; ++r) o[nt][r] *= al[r];

#pragma unroll
      for (int kc = 0; kc < 2; ++kc) {
        short8v pf = *(const short8v*)&pw[c * LDW + kc * 32 + q4 * 8];
#pragma unroll
        for (int nt = 0; nt < 4; ++nt) {
          short8v vf = *(const short8v*)&Vs[(nt * 16 + c) * LDW + kc * 32 + q4 * 8];
          o[nt] = __builtin_amdgcn_mfma_f32_16x16x32_bf16(pf, vf, o[nt], 0, 0, 0);
        }
      }
    }

    int qrow[4]; bool msk[4]; float inv[4];
#pragma unroll
    for (int r = 0; r < 4; ++r) {
      qrow[r] = rowbase + q4 * 4 + r;
      msk[r] = (mask[b * TT + qrow[r]] == 0);
      inv[r] = 1.f / l_i[r];
    }
#pragma unroll
    for (int nt = 0; nt < 4; ++nt) {
      int d = nt * 16 + c;
      float mv = meanv[bh * HD + d];
#pragma unroll
      for (int r = 0; r < 4; ++r) {
        float val = msk[r] ? mv : o[nt][r] * inv[r];
        outb[((size_t)(b * TT + qrow[r])) * CC + h * HD + d] = f2bf(val);
      }
    }
  }
}

// ---------------- launcher ----------------
extern "C" void kernel_launch(void* const* d_in, const int* in_sizes, int n_in,
                              void* d_out, int out_size, void* d_ws, size_t ws_size,
                              hipStream_t stream)
{
  (void)in_sizes; (void)n_in; (void)out_size; (void)ws_size;
  const float* x     = (const float*)d_in[0];
  const int*   mask  = (const int*)d_in[1];
  const float* Wattn = (const float*)d_in[2];
  const float* battn = (const float*)d_in[3];
  const float* Wproj = (const float*)d_in[4];
  const float* bproj = (const float*)d_in[5];
  float* out = (float*)d_out;

  char* ws = (char*)d_ws;
  size_t off = 0;
  auto alloc = [&](size_t bytes) -> void* {
    void* p = ws + off;
    off += (bytes + 255) & ~(size_t)255;
    return p;
  };
  u16* WtA  = (u16*)alloc((size_t)NQKV * KD * 2);
  u16* WtP  = (u16*)alloc((size_t)CC * CC * 2);
  u16* xb   = (u16*)alloc((size_t)MROWS * CC * 2);
  u16* qbuf = (u16*)alloc((size_t)MROWS * CC * 2);
  u16* kbuf = (u16*)alloc((size_t)MROWS * CC * 2);
  u16* vbuf = (u16*)alloc((size_t)MROWS * CC * 2);
  u16* vtb  = (u16*)alloc((size_t)MROWS * CC * 2);   // [bh][d][t]
  u16* abuf = (u16*)alloc((size_t)MROWS * CC * 2);
  float* mv = (float*)alloc((size_t)BH * HD * 4);

  int nx = MROWS * CC;
  convert_f32_bf16<<<nx / (256 * 4), 256, 0, stream>>>(x, xb, nx);
  transpose_f32_bf16<<<(NQKV/32)*(KD/32), 256, 0, stream>>>(Wattn, WtA, KD, NQKV);
  transpose_f32_bf16<<<(CC/32)*(CC/32),   256, 0, stream>>>(Wproj, WtP, CC, CC);

  gemm_bt<<<(MROWS/128)*(NQKV/128), 256, 0, stream>>>(
      xb, WtA, battn, nullptr, qbuf, kbuf, vbuf, MROWS, NQKV, 0);

  transpose_v<<<BH * (TT/64), 256, 0, stream>>>(vbuf, vtb);
  vmean_kernel<<<BH, 64, 0, stream>>>(vbuf, mv);

  attn_kernel<<<BH * 8, 256, 0, stream>>>(qbuf, kbuf, vtb, mask, mv, abuf);

  gemm_bt<<<(MROWS/128)*(CC/128), 256, 0, stream>>>(
      abuf, WtP, bproj, out, nullptr, nullptr, nullptr, MROWS, CC, 1);
}

// Round 7
// 237.114 us; speedup vs baseline: 3.2755x; 1.0528x over previous
//
#include <hip/hip_runtime.h>

#define BQ 8
#define TT 1024
#define CC 768
#define NH 12
#define HD 64
#define BH (BQ*NH)      // 96
#define MROWS (BQ*TT)   // 8192
#define NQKV (3*CC)     // 2304
#define KD CC           // 768

typedef unsigned short u16;
typedef __attribute__((ext_vector_type(4))) short short4v;
typedef __attribute__((ext_vector_type(8))) short short8v;
typedef __attribute__((ext_vector_type(4))) float floatx4;
typedef __attribute__((address_space(1))) const unsigned int gu32;
typedef __attribute__((address_space(3))) unsigned int lu32;

__device__ __forceinline__ float bf2f(u16 u) {
  union { unsigned int i; float f; } c; c.i = ((unsigned int)u) << 16; return c.f;
}
__device__ __forceinline__ u16 f2bf(float f) {
  union { float f; unsigned int i; } c; c.f = f;
  unsigned int i = c.i;
  return (u16)((i + 0x7FFFu + ((i >> 16) & 1u)) >> 16);  // RNE
}
__device__ __forceinline__ float fast_exp2(float x) {
  return __builtin_amdgcn_exp2f(x);   // v_exp_f32 (base-2)
}
// async global->LDS, 16 B per lane; LDS dest = wave-uniform base + lane*16
__device__ __forceinline__ void async_ld16(const u16* g, u16* l) {
  __builtin_amdgcn_global_load_lds((gu32*)g, (lu32*)l, 16, 0, 0);
}

// ---------------- elementwise f32 -> bf16 ----------------
__global__ __launch_bounds__(256) void convert_f32_bf16(
    const float* __restrict__ in, u16* __restrict__ out, int n)
{
  int i = (blockIdx.x * 256 + threadIdx.x) * 4;
  if (i >= n) return;
  floatx4 v = *(const floatx4*)(in + i);
  short4v o;
  o[0] = (short)f2bf(v[0]); o[1] = (short)f2bf(v[1]);
  o[2] = (short)f2bf(v[2]); o[3] = (short)f2bf(v[3]);
  *(short4v*)(out + i) = o;
}

// ---------- transpose f32 [R,Cc] -> bf16 [Cc,R] ----------
__global__ __launch_bounds__(256) void transpose_f32_bf16(
    const float* __restrict__ in, u16* __restrict__ out, int R, int Cc)
{
  __shared__ float tile[32][33];
  int ct = Cc >> 5;
  int bx = blockIdx.x % ct;
  int by = blockIdx.x / ct;
  int tx = threadIdx.x & 31;
  int ty = threadIdx.x >> 5;    // 0..7
  int c0 = bx << 5, r0 = by << 5;
#pragma unroll
  for (int s = 0; s < 4; ++s)
    tile[ty + s*8][tx] = in[(size_t)(r0 + ty + s*8) * Cc + c0 + tx];
  __syncthreads();
#pragma unroll
  for (int s = 0; s < 4; ++s)
    out[(size_t)(c0 + ty + s*8) * R + r0 + tx] = f2bf(tile[tx][ty + s*8]);
}

// ------- GEMM: 64x128 tile, BK=32, global_load_lds staging, 5 blocks/CU -------
// C[M,N] = A[M,K] * Bt[N,K]^T + bias. mode 0: scatter q/k/v bf16; mode 1: f32 out.
// Wave w covers M-quadrant (w>>1)*32 (2 mtiles), N-quadrant (w&1)*64 (4 ntiles):
// acc 2x4 floatx4 = 32 AGPR -> ~5 waves/SIMD resident (vs 128x128's 3).
__global__ __launch_bounds__(256) void gemm_bt(
    const u16* __restrict__ A, const u16* __restrict__ Bt,
    const float* __restrict__ bias,
    float* __restrict__ out,
    u16* __restrict__ qo, u16* __restrict__ ko, u16* __restrict__ vo,
    int M, int N, int mode)
{
  __shared__ u16 As[64 * 32];    // [row][k], UNPADDED (global_load_lds lane order)
  __shared__ u16 Bs[128 * 32];

  int tid = threadIdx.x;
  int lane = tid & 63;
  int w = tid >> 6;
  int c = lane & 15;     // fragment col
  int q4 = lane >> 4;    // quad

  int mtiles = M >> 6;
  int mt = blockIdx.x % mtiles;
  int nt = blockIdx.x / mtiles;
  int m0 = mt << 6, n0 = nt << 7;

  int wr = (w >> 1) << 5;   // 0 / 32
  int wc = (w & 1) << 6;    // 0 / 64

  // staging: wave w stages A rows [w*16,w*16+16) (1 inst) and B rows [w*32,w*32+32) (2)
  int srow = lane >> 2;          // 0..15
  int sk = (lane & 3) << 3;      // chunk of 8 shorts (16 B)
  const u16* ag = A + (size_t)(m0 + w * 16 + srow) * KD + sk;
  const u16* bg = Bt + (size_t)(n0 + w * 32 + srow) * KD + sk;
  u16* asl = &As[(w * 16) * 32];   // wave-uniform LDS bases
  u16* bsl = &Bs[(w * 32) * 32];

  floatx4 acc[2][4];
#pragma unroll
  for (int mi = 0; mi < 2; ++mi)
#pragma unroll
    for (int ni = 0; ni < 4; ++ni) acc[mi][ni] = (floatx4){0.f, 0.f, 0.f, 0.f};

#pragma unroll 1
  for (int kt = 0; kt < KD; kt += 32) {
    async_ld16(ag + kt,            asl);
    async_ld16(bg + kt,            bsl);
    async_ld16(bg + kt + 16 * KD,  bsl + 16 * 32);
    __syncthreads();   // drains vmcnt(0): LDS tiles complete

    short8v af[2], bf[4];
#pragma unroll
    for (int mi = 0; mi < 2; ++mi)
      af[mi] = *(const short8v*)&As[(wr + mi * 16 + c) * 32 + q4 * 8];
#pragma unroll
    for (int ni = 0; ni < 4; ++ni)
      bf[ni] = *(const short8v*)&Bs[(wc + ni * 16 + c) * 32 + q4 * 8];
#pragma unroll
    for (int mi = 0; mi < 2; ++mi)
#pragma unroll
      for (int ni = 0; ni < 4; ++ni)
        acc[mi][ni] = __builtin_amdgcn_mfma_f32_16x16x32_bf16(af[mi], bf[ni], acc[mi][ni], 0, 0, 0);
    __syncthreads();   // all reads done before next stage overwrites
  }

  // epilogue
  if (mode == 0) {
    int which = (n0 + wc) / CC;            // wave-uniform: 64-col span within one of q/k/v
    int nbase = (n0 + wc) - which * CC;
    u16* dst0 = (which == 0) ? qo : ((which == 1) ? ko : vo);
#pragma unroll
    for (int ni = 0; ni < 4; ++ni) {
      int nn = nbase + ni * 16 + c;        // 0..767 within q/k/v
      int hh = nn >> 6, dd = nn & 63;
      float bv = bias[which * CC + nn];
#pragma unroll
      for (int mi = 0; mi < 2; ++mi) {
#pragma unroll
        for (int r = 0; r < 4; ++r) {
          int mm = m0 + wr + mi * 16 + q4 * 4 + r;
          int bb = mm >> 10, tt = mm & 1023;
          size_t idx = (((size_t)(bb * NH + hh)) * TT + tt) * HD + dd;
          dst0[idx] = f2bf(acc[mi][ni][r] + bv);
        }
      }
    }
  } else {
#pragma unroll
    for (int ni = 0; ni < 4; ++ni) {
      int nn = n0 + wc + ni * 16 + c;
      float bv = bias[nn];
#pragma unroll
      for (int mi = 0; mi < 2; ++mi) {
#pragma unroll
        for (int r = 0; r < 4; ++r) {
          int mm = m0 + wr + mi * 16 + q4 * 4 + r;
          out[(size_t)mm * N + nn] = acc[mi][ni][r] + bv;
        }
      }
    }
  }
}

// ---------------- V transpose: vbuf [bh][t][d] -> vtb [bh][d][t] ----------------
__global__ __launch_bounds__(256) void transpose_v(
    const u16* __restrict__ vb, u16* __restrict__ vt)
{
  __shared__ u16 tile[64][72];
  int tid = threadIdx.x;
  int tt0 = (blockIdx.x & 15) << 6;
  int bh = blockIdx.x >> 4;
  {
    int trow = tid >> 2;
    int dchunk = (tid & 3) << 4;
    const u16* src = vb + (((size_t)bh * TT + tt0 + trow) * HD) + dchunk;
    *(short8v*)&tile[trow][dchunk]     = *(const short8v*)src;
    *(short8v*)&tile[trow][dchunk + 8] = *(const short8v*)(src + 8);
  }
  __syncthreads();
  {
    int drow = tid >> 2;
    int tchunk = (tid & 3) << 4;
    short8v a, bv;
#pragma unroll
    for (int j = 0; j < 8; ++j) {
      a[j]  = (short)tile[tchunk + j][drow];
      bv[j] = (short)tile[tchunk + 8 + j][drow];
    }
    u16* dst = vt + ((size_t)bh * HD + drow) * TT + tt0 + tchunk;
    *(short8v*)dst       = a;
    *(short8v*)(dst + 8) = bv;
  }
}

// ---------------- mean of V over T, per (b,h,d) ----------------
__global__ __launch_bounds__(64) void vmean_kernel(
    const u16* __restrict__ vb, float* __restrict__ mv)
{
  int bh = blockIdx.x;
  int d = threadIdx.x;
  const u16* p = vb + (size_t)bh * TT * HD + d;
  float s0 = 0.f, s1 = 0.f, s2 = 0.f, s3 = 0.f;
  for (int t = 0; t < TT; t += 4) {
    s0 += bf2f(p[(size_t)(t + 0) * HD]);
    s1 += bf2f(p[(size_t)(t + 1) * HD]);
    s2 += bf2f(p[(size_t)(t + 2) * HD]);
    s3 += bf2f(p[(size_t)(t + 3) * HD]);
  }
  mv[bh * HD + d] = (s0 + s1 + s2 + s3) * (1.0f / 1024.0f);
}

// ---------------- MFMA flash attention (balanced pairs + pipelined staging) ----------------
#define LDW 72
#define SCL 0.18033688f   // (1/sqrt(64)) * log2(e); softmax in exp2 domain

__global__ __launch_bounds__(256) void attn_kernel(
    const u16* __restrict__ qb, const u16* __restrict__ kb,
    const u16* __restrict__ vtb, const int* __restrict__ mask,
    const float* __restrict__ meanv, u16* __restrict__ outb)
{
  __shared__ u16 Ks[64 * LDW];       // K tile [key][d]
  __shared__ u16 Vs[64 * LDW];       // V^T tile [d][key]
  __shared__ u16 Ps[4][16 * LDW];    // per-wave P [row][key]

  int tid = threadIdx.x;
  int lane = tid & 63;
  int w = tid >> 6;
  int c = lane & 15;
  int q4 = lane >> 4;

  int pair = blockIdx.x & 7;
  int bh = blockIdx.x >> 3;
  int b = bh / NH;
  int h = bh - b * NH;

  int srow = tid >> 2;
  int schunk = (tid & 3) << 4;
  const u16* kgp = kb + ((size_t)bh * TT + srow) * HD + schunk;
  const u16* vgp = vtb + ((size_t)bh * HD + srow) * TT + schunk;
  u16* ksw = &Ks[srow * LDW + schunk];
  u16* vsw = &Vs[srow * LDW + schunk];
  u16* pw = &Ps[w][0];

#pragma unroll 1
  for (int phase = 0; phase < 2; ++phase) {
    int qt = phase ? (15 - pair) : pair;
    int rowbase = (qt << 6) + (w << 4);

    short8v qfrag[2];
    {
      const u16* qp = qb + ((size_t)bh * TT + rowbase + c) * HD + q4 * 8;
      qfrag[0] = *(const short8v*)qp;
      qfrag[1] = *(const short8v*)(qp + 32);
    }

    floatx4 o[4];
#pragma unroll
    for (int i = 0; i < 4; ++i) o[i] = (floatx4){0.f, 0.f, 0.f, 0.f};
    float m_i[4], l_i[4];
#pragma unroll
    for (int r = 0; r < 4; ++r) { m_i[r] = -INFINITY; l_i[r] = 0.f; }

    short8v kr0, kr1, vr0, vr1;
    kr0 = *(const short8v*)kgp;
    kr1 = *(const short8v*)(kgp + 8);
    vr0 = *(const short8v*)vgp;
    vr1 = *(const short8v*)(vgp + 8);

#pragma unroll 1
    for (int kt = 0; kt <= qt; ++kt) {
      __syncthreads();
      *(short8v*)ksw = kr0; *(short8v*)(ksw + 8) = kr1;
      *(short8v*)vsw = vr0; *(short8v*)(vsw + 8) = vr1;
      __syncthreads();

      if (kt < qt) {
        const u16* kp = kgp + ((size_t)(kt + 1) << 6) * HD;
        const u16* vp = vgp + ((kt + 1) << 6);
        kr0 = *(const short8v*)kp;
        kr1 = *(const short8v*)(kp + 8);
        vr0 = *(const short8v*)vp;
        vr1 = *(const short8v*)(vp + 8);
      }

      floatx4 s[4];
#pragma unroll
      for (int nt = 0; nt < 4; ++nt) s[nt] = (floatx4){0.f, 0.f, 0.f, 0.f};
#pragma unroll
      for (int kc = 0; kc < 2; ++kc) {
#pragma unroll
        for (int nt = 0; nt < 4; ++nt) {
          short8v kf = *(const short8v*)&Ks[(nt * 16 + c) * LDW + kc * 32 + q4 * 8];
          s[nt] = __builtin_amdgcn_mfma_f32_16x16x32_bf16(qfrag[kc], kf, s[nt], 0, 0, 0);
        }
      }

      if (kt == qt) {
#pragma unroll
        for (int nt = 0; nt < 4; ++nt)
#pragma unroll
          for (int r = 0; r < 4; ++r) {
            float sv = s[nt][r] * SCL;
            if (nt * 16 + c > (w << 4) + q4 * 4 + r) sv = -INFINITY;
            s[nt][r] = sv;
          }
      } else {
#pragma unroll
        for (int nt = 0; nt < 4; ++nt)
#pragma unroll
          for (int r = 0; r < 4; ++r) s[nt][r] *= SCL;
      }

      float mt[4];
#pragma unroll
      for (int r = 0; r < 4; ++r)
        mt[r] = fmaxf(fmaxf(s[0][r], s[1][r]), fmaxf(s[2][r], s[3][r]));
#pragma unroll
      for (int r = 0; r < 4; ++r) {
        mt[r] = fmaxf(mt[r], __shfl_xor(mt[r], 1));
        mt[r] = fmaxf(mt[r], __shfl_xor(mt[r], 2));
        mt[r] = fmaxf(mt[r], __shfl_xor(mt[r], 4));
        mt[r] = fmaxf(mt[r], __shfl_xor(mt[r], 8));
      }

      float al[4];
#pragma unroll
      for (int r = 0; r < 4; ++r) {
        float mn = fmaxf(m_i[r], mt[r]);
        al[r] = fast_exp2(m_i[r] - mn);
        m_i[r] = mn;
      }

      float ps[4] = {0.f, 0.f, 0.f, 0.f};
#pragma unroll
      for (int nt = 0; nt < 4; ++nt)
#pragma unroll
        for (int r = 0; r < 4; ++r) {
          float p = fast_exp2(s[nt][r] - m_i[r]);
          ps[r] += p;
          pw[(q4 * 4 + r) * LDW + nt * 16 + c] = f2bf(p);
        }
#pragma unroll
      for (int r = 0; r < 4; ++r) {
        ps[r] += __shfl_xor(ps[r], 1);
        ps[r] += __shfl_xor(ps[r], 2);
        ps[r] += __shfl_xor(ps[r], 4);
        ps[r] += __shfl_xor(ps[r], 8);
        l_i[r] = l_i[r] * al[r] + ps[r];
      }
#pragma unroll
      for (int nt = 0; nt < 4; ++nt)
#pragma unroll
        for (int r = 0; r < 4; ++r) o[nt][r] *= al[r];

#pragma unroll
      for (int kc = 0; kc < 2; ++kc) {
        short8v pf = *(const short8v*)&pw[c * LDW + kc * 32 + q4 * 8];
#pragma unroll
        for (int nt = 0; nt < 4; ++nt) {
          short8v vf = *(const short8v*)&Vs[(nt * 16 + c) * LDW + kc * 32 + q4 * 8];
          o[nt] = __builtin_amdgcn_mfma_f32_16x16x32_bf16(pf, vf, o[nt], 0, 0, 0);
        }
      }
    }

    int qrow[4]; bool msk[4]; float inv[4];
#pragma unroll
    for (int r = 0; r < 4; ++r) {
      qrow[r] = rowbase + q4 * 4 + r;
      msk[r] = (mask[b * TT + qrow[r]] == 0);
      inv[r] = 1.f / l_i[r];
    }
#pragma unroll
    for (int nt = 0; nt < 4; ++nt) {
      int d = nt * 16 + c;
      float mv = meanv[bh * HD + d];
#pragma unroll
      for (int r = 0; r < 4; ++r) {
        float val = msk[r] ? mv : o[nt][r] * inv[r];
        outb[((size_t)(b * TT + qrow[r])) * CC + h * HD + d] = f2bf(val);
      }
    }
  }
}

// ---------------- launcher ----------------
extern "C" void kernel_launch(void* const* d_in, const int* in_sizes, int n_in,
                              void* d_out, int out_size, void* d_ws, size_t ws_size,
                              hipStream_t stream)
{
  (void)in_sizes; (void)n_in; (void)out_size; (void)ws_size;
  const float* x     = (const float*)d_in[0];
  const int*   mask  = (const int*)d_in[1];
  const float* Wattn = (const float*)d_in[2];
  const float* battn = (const float*)d_in[3];
  const float* Wproj = (const float*)d_in[4];
  const float* bproj = (const float*)d_in[5];
  float* out = (float*)d_out;

  char* ws = (char*)d_ws;
  size_t off = 0;
  auto alloc = [&](size_t bytes) -> void* {
    void* p = ws + off;
    off += (bytes + 255) & ~(size_t)255;
    return p;
  };
  u16* WtA  = (u16*)alloc((size_t)NQKV * KD * 2);
  u16* WtP  = (u16*)alloc((size_t)CC * CC * 2);
  u16* xb   = (u16*)alloc((size_t)MROWS * CC * 2);
  u16* qbuf = (u16*)alloc((size_t)MROWS * CC * 2);
  u16* kbuf = (u16*)alloc((size_t)MROWS * CC * 2);
  u16* vbuf = (u16*)alloc((size_t)MROWS * CC * 2);
  u16* vtb  = (u16*)alloc((size_t)MROWS * CC * 2);   // [bh][d][t]
  u16* abuf = (u16*)alloc((size_t)MROWS * CC * 2);
  float* mv = (float*)alloc((size_t)BH * HD * 4);

  int nx = MROWS * CC;
  convert_f32_bf16<<<nx / (256 * 4), 256, 0, stream>>>(x, xb, nx);
  transpose_f32_bf16<<<(NQKV/32)*(KD/32), 256, 0, stream>>>(Wattn, WtA, KD, NQKV);
  transpose_f32_bf16<<<(CC/32)*(CC/32),   256, 0, stream>>>(Wproj, WtP, CC, CC);

  gemm_bt<<<(MROWS/64)*(NQKV/128), 256, 0, stream>>>(
      xb, WtA, battn, nullptr, qbuf, kbuf, vbuf, MROWS, NQKV, 0);

  transpose_v<<<BH * (TT/64), 256, 0, stream>>>(vbuf, vtb);
  vmean_kernel<<<BH, 64, 0, stream>>>(vbuf, mv);

  attn_kernel<<<BH * 8, 256, 0, stream>>>(qbuf, kbuf, vtb, mask, mv, abuf);

  gemm_bt<<<(MROWS/64)*(CC/128), 256, 0, stream>>>(
      abuf, WtP, bproj, out, nullptr, nullptr, nullptr, MROWS, CC, 1);
}

// Round 8
// 218.518 us; speedup vs baseline: 3.5543x; 1.0851x over previous
//
#include <hip/hip_runtime.h>

#define BQ 8
#define TT 1024
#define CC 768
#define NH 12
#define HD 64
#define BH (BQ*NH)      // 96
#define MROWS (BQ*TT)   // 8192
#define NQKV (3*CC)     // 2304
#define KD CC           // 768

typedef unsigned short u16;
typedef __attribute__((ext_vector_type(4))) short short4v;
typedef __attribute__((ext_vector_type(8))) short short8v;
typedef __attribute__((ext_vector_type(4))) float floatx4;
typedef __attribute__((address_space(1))) const unsigned int gu32;
typedef __attribute__((address_space(3))) unsigned int lu32;

__device__ __forceinline__ float bf2f(u16 u) {
  union { unsigned int i; float f; } c; c.i = ((unsigned int)u) << 16; return c.f;
}
__device__ __forceinline__ u16 f2bf(float f) {
  union { float f; unsigned int i; } c; c.f = f;
  unsigned int i = c.i;
  return (u16)((i + 0x7FFFu + ((i >> 16) & 1u)) >> 16);  // RNE
}
__device__ __forceinline__ float fast_exp2(float x) {
  return __builtin_amdgcn_exp2f(x);   // v_exp_f32 (base-2)
}
// async global->LDS, 16 B per lane; LDS dest = wave-uniform base + lane*16
__device__ __forceinline__ void async_ld16(const u16* g, u16* l) {
  __builtin_amdgcn_global_load_lds((gu32*)g, (lu32*)l, 16, 0, 0);
}

// ---------------- elementwise f32 -> bf16 ----------------
__global__ __launch_bounds__(256) void convert_f32_bf16(
    const float* __restrict__ in, u16* __restrict__ out, int n)
{
  int i = (blockIdx.x * 256 + threadIdx.x) * 4;
  if (i >= n) return;
  floatx4 v = *(const floatx4*)(in + i);
  short4v o;
  o[0] = (short)f2bf(v[0]); o[1] = (short)f2bf(v[1]);
  o[2] = (short)f2bf(v[2]); o[3] = (short)f2bf(v[3]);
  *(short4v*)(out + i) = o;
}

// ---------- transpose f32 [R,Cc] -> bf16 [Cc,R] ----------
__global__ __launch_bounds__(256) void transpose_f32_bf16(
    const float* __restrict__ in, u16* __restrict__ out, int R, int Cc)
{
  __shared__ float tile[32][33];
  int ct = Cc >> 5;
  int bx = blockIdx.x % ct;
  int by = blockIdx.x / ct;
  int tx = threadIdx.x & 31;
  int ty = threadIdx.x >> 5;    // 0..7
  int c0 = bx << 5, r0 = by << 5;
#pragma unroll
  for (int s = 0; s < 4; ++s)
    tile[ty + s*8][tx] = in[(size_t)(r0 + ty + s*8) * Cc + c0 + tx];
  __syncthreads();
#pragma unroll
  for (int s = 0; s < 4; ++s)
    out[(size_t)(c0 + ty + s*8) * R + r0 + tx] = f2bf(tile[tx][ty + s*8]);
}

// ------- GEMM: 64x128 tile, BK=64, global_load_lds + XOR bank swizzle -------
// C[M,N] = A[M,K] * Bt[N,K]^T + bias. mode 0: scatter q/k/v bf16; mode 1: f32 out.
// LDS rows are 64 shorts (128 B); 16-B unit u of row r stored at phys unit
// u ^ (r&7) -> fragment ds_read_b128 tiles all 32 banks (conflict-free).
// Swizzle applied on the GLOBAL source address (per-lane free); LDS side of
// global_load_lds stays lane-contiguous as required.
__global__ __launch_bounds__(256) void gemm_bt(
    const u16* __restrict__ A, const u16* __restrict__ Bt,
    const float* __restrict__ bias,
    float* __restrict__ out,
    u16* __restrict__ qo, u16* __restrict__ ko, u16* __restrict__ vo,
    int M, int N, int mode)
{
  __shared__ u16 As[64 * 64];    // [row][64k], swizzled units
  __shared__ u16 Bs[128 * 64];

  int tid = threadIdx.x;
  int lane = tid & 63;
  int w = tid >> 6;
  int c = lane & 15;     // fragment col
  int q4 = lane >> 4;    // quad

  int mtiles = M >> 6;
  int mt = blockIdx.x % mtiles;
  int nt = blockIdx.x / mtiles;
  int m0 = mt << 6, n0 = nt << 7;

  int wr = (w >> 1) << 5;   // 0 / 32
  int wc = (w & 1) << 6;    // 0 / 64

  // staging: each inst covers 8 rows x 64k (8 lanes/row, 16 B each).
  // lane: row_off = lane>>3, unit u_s = lane&7 holds global unit u_s ^ (lane>>3).
  int srow8 = lane >> 3;                      // 0..7
  int ug = ((lane & 7) ^ srow8) << 3;         // swizzled global k-offset (shorts)
  const u16* ag = A  + (size_t)(m0 + w * 16 + srow8) * KD + ug;   // +i*8 rows per inst
  const u16* bg = Bt + (size_t)(n0 + w * 32 + srow8) * KD + ug;
  u16* asl = &As[(w * 16) * 64];   // wave-uniform LDS bases
  u16* bsl = &Bs[(w * 32) * 64];

  floatx4 acc[2][4];
#pragma unroll
  for (int mi = 0; mi < 2; ++mi)
#pragma unroll
    for (int ni = 0; ni < 4; ++ni) acc[mi][ni] = (floatx4){0.f, 0.f, 0.f, 0.f};

  // fragment LDS offsets (swizzled): row*64 + ((kc*4+q4)^(c&7))*8
  int c7 = c & 7;

#pragma unroll 1
  for (int kt = 0; kt < KD; kt += 64) {
    async_ld16(ag + kt,              asl);
    async_ld16(ag + kt + 8 * KD,     asl + 8 * 64);
    async_ld16(bg + kt,              bsl);
    async_ld16(bg + kt + 8 * KD,     bsl + 8 * 64);
    async_ld16(bg + kt + 16 * KD,    bsl + 16 * 64);
    async_ld16(bg + kt + 24 * KD,    bsl + 24 * 64);
    __syncthreads();   // drains vmcnt(0): LDS tiles complete

    short8v af[2][2], bf[4][2];
#pragma unroll
    for (int kc = 0; kc < 2; ++kc) {
      int uoff = ((kc * 4 + q4) ^ c7) << 3;
#pragma unroll
      for (int mi = 0; mi < 2; ++mi)
        af[mi][kc] = *(const short8v*)&As[(wr + mi * 16 + c) * 64 + uoff];
#pragma unroll
      for (int ni = 0; ni < 4; ++ni)
        bf[ni][kc] = *(const short8v*)&Bs[(wc + ni * 16 + c) * 64 + uoff];
    }
#pragma unroll
    for (int kc = 0; kc < 2; ++kc)
#pragma unroll
      for (int mi = 0; mi < 2; ++mi)
#pragma unroll
        for (int ni = 0; ni < 4; ++ni)
          acc[mi][ni] = __builtin_amdgcn_mfma_f32_16x16x32_bf16(af[mi][kc], bf[ni][kc], acc[mi][ni], 0, 0, 0);
    __syncthreads();   // all reads done before next stage overwrites
  }

  // epilogue
  if (mode == 0) {
    int which = (n0 + wc) / CC;            // wave-uniform: 64-col span within one of q/k/v
    int nbase = (n0 + wc) - which * CC;
    u16* dst0 = (which == 0) ? qo : ((which == 1) ? ko : vo);
#pragma unroll
    for (int ni = 0; ni < 4; ++ni) {
      int nn = nbase + ni * 16 + c;        // 0..767 within q/k/v
      int hh = nn >> 6, dd = nn & 63;
      float bv = bias[which * CC + nn];
#pragma unroll
      for (int mi = 0; mi < 2; ++mi) {
#pragma unroll
        for (int r = 0; r < 4; ++r) {
          int mm = m0 + wr + mi * 16 + q4 * 4 + r;
          int bb = mm >> 10, tt = mm & 1023;
          size_t idx = (((size_t)(bb * NH + hh)) * TT + tt) * HD + dd;
          dst0[idx] = f2bf(acc[mi][ni][r] + bv);
        }
      }
    }
  } else {
#pragma unroll
    for (int ni = 0; ni < 4; ++ni) {
      int nn = n0 + wc + ni * 16 + c;
      float bv = bias[nn];
#pragma unroll
      for (int mi = 0; mi < 2; ++mi) {
#pragma unroll
        for (int r = 0; r < 4; ++r) {
          int mm = m0 + wr + mi * 16 + q4 * 4 + r;
          out[(size_t)mm * N + nn] = acc[mi][ni][r] + bv;
        }
      }
    }
  }
}

// ---------------- V transpose: vbuf [bh][t][d] -> vtb [bh][d][t] ----------------
__global__ __launch_bounds__(256) void transpose_v(
    const u16* __restrict__ vb, u16* __restrict__ vt)
{
  __shared__ u16 tile[64][72];
  int tid = threadIdx.x;
  int tt0 = (blockIdx.x & 15) << 6;
  int bh = blockIdx.x >> 4;
  {
    int trow = tid >> 2;
    int dchunk = (tid & 3) << 4;
    const u16* src = vb + (((size_t)bh * TT + tt0 + trow) * HD) + dchunk;
    *(short8v*)&tile[trow][dchunk]     = *(const short8v*)src;
    *(short8v*)&tile[trow][dchunk + 8] = *(const short8v*)(src + 8);
  }
  __syncthreads();
  {
    int drow = tid >> 2;
    int tchunk = (tid & 3) << 4;
    short8v a, bv;
#pragma unroll
    for (int j = 0; j < 8; ++j) {
      a[j]  = (short)tile[tchunk + j][drow];
      bv[j] = (short)tile[tchunk + 8 + j][drow];
    }
    u16* dst = vt + ((size_t)bh * HD + drow) * TT + tt0 + tchunk;
    *(short8v*)dst       = a;
    *(short8v*)(dst + 8) = bv;
  }
}

// ---------------- mean of V over T, per (b,h,d) ----------------
__global__ __launch_bounds__(64) void vmean_kernel(
    const u16* __restrict__ vb, float* __restrict__ mv)
{
  int bh = blockIdx.x;
  int d = threadIdx.x;
  const u16* p = vb + (size_t)bh * TT * HD + d;
  float s0 = 0.f, s1 = 0.f, s2 = 0.f, s3 = 0.f;
  for (int t = 0; t < TT; t += 4) {
    s0 += bf2f(p[(size_t)(t + 0) * HD]);
    s1 += bf2f(p[(size_t)(t + 1) * HD]);
    s2 += bf2f(p[(size_t)(t + 2) * HD]);
    s3 += bf2f(p[(size_t)(t + 3) * HD]);
  }
  mv[bh * HD + d] = (s0 + s1 + s2 + s3) * (1.0f / 1024.0f);
}

// ---------------- MFMA flash attention (balanced pairs + pipelined staging) ----------------
#define LDW 72
#define SCL 0.18033688f   // (1/sqrt(64)) * log2(e); softmax in exp2 domain

__global__ __launch_bounds__(256) void attn_kernel(
    const u16* __restrict__ qb, const u16* __restrict__ kb,
    const u16* __restrict__ vtb, const int* __restrict__ mask,
    const float* __restrict__ meanv, u16* __restrict__ outb)
{
  __shared__ u16 Ks[64 * LDW];       // K tile [key][d]
  __shared__ u16 Vs[64 * LDW];       // V^T tile [d][key]
  __shared__ u16 Ps[4][16 * LDW];    // per-wave P [row][key]

  int tid = threadIdx.x;
  int lane = tid & 63;
  int w = tid >> 6;
  int c = lane & 15;
  int q4 = lane >> 4;

  int pair = blockIdx.x & 7;
  int bh = blockIdx.x >> 3;
  int b = bh / NH;
  int h = bh - b * NH;

  int srow = tid >> 2;
  int schunk = (tid & 3) << 4;
  const u16* kgp = kb + ((size_t)bh * TT + srow) * HD + schunk;
  const u16* vgp = vtb + ((size_t)bh * HD + srow) * TT + schunk;
  u16* ksw = &Ks[srow * LDW + schunk];
  u16* vsw = &Vs[srow * LDW + schunk];
  u16* pw = &Ps[w][0];

#pragma unroll 1
  for (int phase = 0; phase < 2; ++phase) {
    int qt = phase ? (15 - pair) : pair;
    int rowbase = (qt << 6) + (w << 4);

    short8v qfrag[2];
    {
      const u16* qp = qb + ((size_t)bh * TT + rowbase + c) * HD + q4 * 8;
      qfrag[0] = *(const short8v*)qp;
      qfrag[1] = *(const short8v*)(qp + 32);
    }

    floatx4 o[4];
#pragma unroll
    for (int i = 0; i < 4; ++i) o[i] = (floatx4){0.f, 0.f, 0.f, 0.f};
    float m_i[4], l_i[4];
#pragma unroll
    for (int r = 0; r < 4; ++r) { m_i[r] = -INFINITY; l_i[r] = 0.f; }

    short8v kr0, kr1, vr0, vr1;
    kr0 = *(const short8v*)kgp;
    kr1 = *(const short8v*)(kgp + 8);
    vr0 = *(const short8v*)vgp;
    vr1 = *(const short8v*)(vgp + 8);

#pragma unroll 1
    for (int kt = 0; kt <= qt; ++kt) {
      __syncthreads();
      *(short8v*)ksw = kr0; *(short8v*)(ksw + 8) = kr1;
      *(short8v*)vsw = vr0; *(short8v*)(vsw + 8) = vr1;
      __syncthreads();

      if (kt < qt) {
        const u16* kp = kgp + ((size_t)(kt + 1) << 6) * HD;
        const u16* vp = vgp + ((kt + 1) << 6);
        kr0 = *(const short8v*)kp;
        kr1 = *(const short8v*)(kp + 8);
        vr0 = *(const short8v*)vp;
        vr1 = *(const short8v*)(vp + 8);
      }

      floatx4 s[4];
#pragma unroll
      for (int nt = 0; nt < 4; ++nt) s[nt] = (floatx4){0.f, 0.f, 0.f, 0.f};
#pragma unroll
      for (int kc = 0; kc < 2; ++kc) {
#pragma unroll
        for (int nt = 0; nt < 4; ++nt) {
          short8v kf = *(const short8v*)&Ks[(nt * 16 + c) * LDW + kc * 32 + q4 * 8];
          s[nt] = __builtin_amdgcn_mfma_f32_16x16x32_bf16(qfrag[kc], kf, s[nt], 0, 0, 0);
        }
      }

      if (kt == qt) {
#pragma unroll
        for (int nt = 0; nt < 4; ++nt)
#pragma unroll
          for (int r = 0; r < 4; ++r) {
            float sv = s[nt][r] * SCL;
            if (nt * 16 + c > (w << 4) + q4 * 4 + r) sv = -INFINITY;
            s[nt][r] = sv;
          }
      } else {
#pragma unroll
        for (int nt = 0; nt < 4; ++nt)
#pragma unroll
          for (int r = 0; r < 4; ++r) s[nt][r] *= SCL;
      }

      float mt[4];
#pragma unroll
      for (int r = 0; r < 4; ++r)
        mt[r] = fmaxf(fmaxf(s[0][r], s[1][r]), fmaxf(s[2][r], s[3][r]));
#pragma unroll
      for (int r = 0; r < 4; ++r) {
        mt[r] = fmaxf(mt[r], __shfl_xor(mt[r], 1));
        mt[r] = fmaxf(mt[r], __shfl_xor(mt[r], 2));
        mt[r] = fmaxf(mt[r], __shfl_xor(mt[r], 4));
        mt[r] = fmaxf(mt[r], __shfl_xor(mt[r], 8));
      }

      float al[4];
#pragma unroll
      for (int r = 0; r < 4; ++r) {
        float mn = fmaxf(m_i[r], mt[r]);
        al[r] = fast_exp2(m_i[r] - mn);
        m_i[r] = mn;
      }

      float ps[4] = {0.f, 0.f, 0.f, 0.f};
#pragma unroll
      for (int nt = 0; nt < 4; ++nt)
#pragma unroll
        for (int r = 0; r < 4; ++r) {
          float p = fast_exp2(s[nt][r] - m_i[r]);
          ps[r] += p;
          pw[(q4 * 4 + r) * LDW + nt * 16 + c] = f2bf(p);
        }
#pragma unroll
      for (int r = 0; r < 4; ++r) {
        ps[r] += __shfl_xor(ps[r], 1);
        ps[r] += __shfl_xor(ps[r], 2);
        ps[r] += __shfl_xor(ps[r], 4);
        ps[r] += __shfl_xor(ps[r], 8);
        l_i[r] = l_i[r] * al[r] + ps[r];
      }
#pragma unroll
      for (int nt = 0; nt < 4; ++nt)
#pragma unroll
        for (int r = 0; r < 4; ++r) o[nt][r] *= al[r];

#pragma unroll
      for (int kc = 0; kc < 2; ++kc) {
        short8v pf = *(const short8v*)&pw[c * LDW + kc * 32 + q4 * 8];
#pragma unroll
        for (int nt = 0; nt < 4; ++nt) {
          short8v vf = *(const short8v*)&Vs[(nt * 16 + c) * LDW + kc * 32 + q4 * 8];
          o[nt] = __builtin_amdgcn_mfma_f32_16x16x32_bf16(pf, vf, o[nt], 0, 0, 0);
        }
      }
    }

    int qrow[4]; bool msk[4]; float inv[4];
#pragma unroll
    for (int r = 0; r < 4; ++r) {
      qrow[r] = rowbase + q4 * 4 + r;
      msk[r] = (mask[b * TT + qrow[r]] == 0);
      inv[r] = 1.f / l_i[r];
    }
#pragma unroll
    for (int nt = 0; nt < 4; ++nt) {
      int d = nt * 16 + c;
      float mv = meanv[bh * HD + d];
#pragma unroll
      for (int r = 0; r < 4; ++r) {
        float val = msk[r] ? mv : o[nt][r] * inv[r];
        outb[((size_t)(b * TT + qrow[r])) * CC + h * HD + d] = f2bf(val);
      }
    }
  }
}

// ---------------- launcher ----------------
extern "C" void kernel_launch(void* const* d_in, const int* in_sizes, int n_in,
                              void* d_out, int out_size, void* d_ws, size_t ws_size,
                              hipStream_t stream)
{
  (void)in_sizes; (void)n_in; (void)out_size; (void)ws_size;
  const float* x     = (const float*)d_in[0];
  const int*   mask  = (const int*)d_in[1];
  const float* Wattn = (const float*)d_in[2];
  const float* battn = (const float*)d_in[3];
  const float* Wproj = (const float*)d_in[4];
  const float* bproj = (const float*)d_in[5];
  float* out = (float*)d_out;

  char* ws = (char*)d_ws;
  size_t off = 0;
  auto alloc = [&](size_t bytes) -> void* {
    void* p = ws + off;
    off += (bytes + 255) & ~(size_t)255;
    return p;
  };
  u16* WtA  = (u16*)alloc((size_t)NQKV * KD * 2);
  u16* WtP  = (u16*)alloc((size_t)CC * CC * 2);
  u16* xb   = (u16*)alloc((size_t)MROWS * CC * 2);
  u16* qbuf = (u16*)alloc((size_t)MROWS * CC * 2);
  u16* kbuf = (u16*)alloc((size_t)MROWS * CC * 2);
  u16* vbuf = (u16*)alloc((size_t)MROWS * CC * 2);
  u16* vtb  = (u16*)alloc((size_t)MROWS * CC * 2);   // [bh][d][t]
  u16* abuf = (u16*)alloc((size_t)MROWS * CC * 2);
  float* mv = (float*)alloc((size_t)BH * HD * 4);

  int nx = MROWS * CC;
  convert_f32_bf16<<<nx / (256 * 4), 256, 0, stream>>>(x, xb, nx);
  transpose_f32_bf16<<<(NQKV/32)*(KD/32), 256, 0, stream>>>(Wattn, WtA, KD, NQKV);
  transpose_f32_bf16<<<(CC/32)*(CC/32),   256, 0, stream>>>(Wproj, WtP, CC, CC);

  gemm_bt<<<(MROWS/64)*(NQKV/128), 256, 0, stream>>>(
      xb, WtA, battn, nullptr, qbuf, kbuf, vbuf, MROWS, NQKV, 0);

  transpose_v<<<BH * (TT/64), 256, 0, stream>>>(vbuf, vtb);
  vmean_kernel<<<BH, 64, 0, stream>>>(vbuf, mv);

  attn_kernel<<<BH * 8, 256, 0, stream>>>(qbuf, kbuf, vtb, mask, mv, abuf);

  gemm_bt<<<(MROWS/64)*(CC/128), 256, 0, stream>>>(
      abuf, WtP, bproj, out, nullptr, nullptr, nullptr, MROWS, CC, 1);
}

// Round 9
// 214.153 us; speedup vs baseline: 3.6267x; 1.0204x over previous
//
#include <hip/hip_runtime.h>

#define BQ 8
#define TT 1024
#define CC 768
#define NH 12
#define HD 64
#define BH (BQ*NH)      // 96
#define MROWS (BQ*TT)   // 8192
#define NQKV (3*CC)     // 2304
#define KD CC           // 768

typedef unsigned short u16;
typedef __attribute__((ext_vector_type(4))) short short4v;
typedef __attribute__((ext_vector_type(8))) short short8v;
typedef __attribute__((ext_vector_type(4))) float floatx4;
typedef __attribute__((address_space(1))) const unsigned int gu32;
typedef __attribute__((address_space(3))) unsigned int lu32;

__device__ __forceinline__ float bf2f(u16 u) {
  union { unsigned int i; float f; } c; c.i = ((unsigned int)u) << 16; return c.f;
}
__device__ __forceinline__ u16 f2bf(float f) {
  union { float f; unsigned int i; } c; c.f = f;
  unsigned int i = c.i;
  return (u16)((i + 0x7FFFu + ((i >> 16) & 1u)) >> 16);  // RNE
}
__device__ __forceinline__ float fast_exp2(float x) {
  return __builtin_amdgcn_exp2f(x);   // v_exp_f32 (base-2)
}
// async global->LDS, 16 B per lane; LDS dest = wave-uniform base + lane*16
__device__ __forceinline__ void async_ld16(const u16* g, u16* l) {
  __builtin_amdgcn_global_load_lds((gu32*)g, (lu32*)l, 16, 0, 0);
}

// ---------------- elementwise f32 -> bf16 ----------------
__global__ __launch_bounds__(256) void convert_f32_bf16(
    const float* __restrict__ in, u16* __restrict__ out, int n)
{
  int i = (blockIdx.x * 256 + threadIdx.x) * 4;
  if (i >= n) return;
  floatx4 v = *(const floatx4*)(in + i);
  short4v o;
  o[0] = (short)f2bf(v[0]); o[1] = (short)f2bf(v[1]);
  o[2] = (short)f2bf(v[2]); o[3] = (short)f2bf(v[3]);
  *(short4v*)(out + i) = o;
}

// ---------- transpose f32 [R,Cc] -> bf16 [Cc,R] ----------
__global__ __launch_bounds__(256) void transpose_f32_bf16(
    const float* __restrict__ in, u16* __restrict__ out, int R, int Cc)
{
  __shared__ float tile[32][33];
  int ct = Cc >> 5;
  int bx = blockIdx.x % ct;
  int by = blockIdx.x / ct;
  int tx = threadIdx.x & 31;
  int ty = threadIdx.x >> 5;    // 0..7
  int c0 = bx << 5, r0 = by << 5;
#pragma unroll
  for (int s = 0; s < 4; ++s)
    tile[ty + s*8][tx] = in[(size_t)(r0 + ty + s*8) * Cc + c0 + tx];
  __syncthreads();
#pragma unroll
  for (int s = 0; s < 4; ++s)
    out[(size_t)(c0 + ty + s*8) * R + r0 + tx] = f2bf(tile[tx][ty + s*8]);
}

// ------- GEMM: 64x128 tile, BK=64, global_load_lds + XOR bank swizzle -------
__global__ __launch_bounds__(256) void gemm_bt(
    const u16* __restrict__ A, const u16* __restrict__ Bt,
    const float* __restrict__ bias,
    float* __restrict__ out,
    u16* __restrict__ qo, u16* __restrict__ ko, u16* __restrict__ vo,
    int M, int N, int mode)
{
  __shared__ u16 As[64 * 64];    // [row][64k], swizzled units
  __shared__ u16 Bs[128 * 64];

  int tid = threadIdx.x;
  int lane = tid & 63;
  int w = tid >> 6;
  int c = lane & 15;     // fragment col
  int q4 = lane >> 4;    // quad

  int mtiles = M >> 6;
  int mt = blockIdx.x % mtiles;
  int nt = blockIdx.x / mtiles;
  int m0 = mt << 6, n0 = nt << 7;

  int wr = (w >> 1) << 5;   // 0 / 32
  int wc = (w & 1) << 6;    // 0 / 64

  int srow8 = lane >> 3;                      // 0..7
  int ug = ((lane & 7) ^ srow8) << 3;         // swizzled global k-offset (shorts)
  const u16* ag = A  + (size_t)(m0 + w * 16 + srow8) * KD + ug;
  const u16* bg = Bt + (size_t)(n0 + w * 32 + srow8) * KD + ug;
  u16* asl = &As[(w * 16) * 64];
  u16* bsl = &Bs[(w * 32) * 64];

  floatx4 acc[2][4];
#pragma unroll
  for (int mi = 0; mi < 2; ++mi)
#pragma unroll
    for (int ni = 0; ni < 4; ++ni) acc[mi][ni] = (floatx4){0.f, 0.f, 0.f, 0.f};

  int c7 = c & 7;

#pragma unroll 1
  for (int kt = 0; kt < KD; kt += 64) {
    async_ld16(ag + kt,              asl);
    async_ld16(ag + kt + 8 * KD,     asl + 8 * 64);
    async_ld16(bg + kt,              bsl);
    async_ld16(bg + kt + 8 * KD,     bsl + 8 * 64);
    async_ld16(bg + kt + 16 * KD,    bsl + 16 * 64);
    async_ld16(bg + kt + 24 * KD,    bsl + 24 * 64);
    __syncthreads();

    short8v af[2][2], bf[4][2];
#pragma unroll
    for (int kc = 0; kc < 2; ++kc) {
      int uoff = ((kc * 4 + q4) ^ c7) << 3;
#pragma unroll
      for (int mi = 0; mi < 2; ++mi)
        af[mi][kc] = *(const short8v*)&As[(wr + mi * 16 + c) * 64 + uoff];
#pragma unroll
      for (int ni = 0; ni < 4; ++ni)
        bf[ni][kc] = *(const short8v*)&Bs[(wc + ni * 16 + c) * 64 + uoff];
    }
#pragma unroll
    for (int kc = 0; kc < 2; ++kc)
#pragma unroll
      for (int mi = 0; mi < 2; ++mi)
#pragma unroll
        for (int ni = 0; ni < 4; ++ni)
          acc[mi][ni] = __builtin_amdgcn_mfma_f32_16x16x32_bf16(af[mi][kc], bf[ni][kc], acc[mi][ni], 0, 0, 0);
    __syncthreads();
  }

  if (mode == 0) {
    int which = (n0 + wc) / CC;
    int nbase = (n0 + wc) - which * CC;
    u16* dst0 = (which == 0) ? qo : ((which == 1) ? ko : vo);
#pragma unroll
    for (int ni = 0; ni < 4; ++ni) {
      int nn = nbase + ni * 16 + c;
      int hh = nn >> 6, dd = nn & 63;
      float bv = bias[which * CC + nn];
#pragma unroll
      for (int mi = 0; mi < 2; ++mi) {
#pragma unroll
        for (int r = 0; r < 4; ++r) {
          int mm = m0 + wr + mi * 16 + q4 * 4 + r;
          int bb = mm >> 10, tt = mm & 1023;
          size_t idx = (((size_t)(bb * NH + hh)) * TT + tt) * HD + dd;
          dst0[idx] = f2bf(acc[mi][ni][r] + bv);
        }
      }
    }
  } else {
#pragma unroll
    for (int ni = 0; ni < 4; ++ni) {
      int nn = n0 + wc + ni * 16 + c;
      float bv = bias[nn];
#pragma unroll
      for (int mi = 0; mi < 2; ++mi) {
#pragma unroll
        for (int r = 0; r < 4; ++r) {
          int mm = m0 + wr + mi * 16 + q4 * 4 + r;
          out[(size_t)mm * N + nn] = acc[mi][ni][r] + bv;
        }
      }
    }
  }
}

// ---------------- V transpose: vbuf [bh][t][d] -> vtb [bh][d][t] ----------------
__global__ __launch_bounds__(256) void transpose_v(
    const u16* __restrict__ vb, u16* __restrict__ vt)
{
  __shared__ u16 tile[64][72];
  int tid = threadIdx.x;
  int tt0 = (blockIdx.x & 15) << 6;
  int bh = blockIdx.x >> 4;
  {
    int trow = tid >> 2;
    int dchunk = (tid & 3) << 4;
    const u16* src = vb + (((size_t)bh * TT + tt0 + trow) * HD) + dchunk;
    *(short8v*)&tile[trow][dchunk]     = *(const short8v*)src;
    *(short8v*)&tile[trow][dchunk + 8] = *(const short8v*)(src + 8);
  }
  __syncthreads();
  {
    int drow = tid >> 2;
    int tchunk = (tid & 3) << 4;
    short8v a, bv;
#pragma unroll
    for (int j = 0; j < 8; ++j) {
      a[j]  = (short)tile[tchunk + j][drow];
      bv[j] = (short)tile[tchunk + 8 + j][drow];
    }
    u16* dst = vt + ((size_t)bh * HD + drow) * TT + tt0 + tchunk;
    *(short8v*)dst       = a;
    *(short8v*)(dst + 8) = bv;
  }
}

// ---------------- mean of V over T, per (b,h,d) ----------------
__global__ __launch_bounds__(64) void vmean_kernel(
    const u16* __restrict__ vb, float* __restrict__ mv)
{
  int bh = blockIdx.x;
  int d = threadIdx.x;
  const u16* p = vb + (size_t)bh * TT * HD + d;
  float s0 = 0.f, s1 = 0.f, s2 = 0.f, s3 = 0.f;
  for (int t = 0; t < TT; t += 4) {
    s0 += bf2f(p[(size_t)(t + 0) * HD]);
    s1 += bf2f(p[(size_t)(t + 1) * HD]);
    s2 += bf2f(p[(size_t)(t + 2) * HD]);
    s3 += bf2f(p[(size_t)(t + 3) * HD]);
  }
  mv[bh * HD + d] = (s0 + s1 + s2 + s3) * (1.0f / 1024.0f);
}

// ---------------- max ||k_t|| per bh (for static softmax bound) ----------------
__global__ __launch_bounds__(256) void knorm_kernel(
    const u16* __restrict__ kb, float* __restrict__ kmaxn)
{
  __shared__ float red[256];
  int bh = blockIdx.x;
  int tid = threadIdx.x;
  float mx = 0.f;
#pragma unroll 1
  for (int t = tid; t < TT; t += 256) {
    const u16* p = kb + ((size_t)bh * TT + t) * HD;
    float s = 0.f;
#pragma unroll
    for (int j = 0; j < 64; j += 8) {
      short8v v = *(const short8v*)(p + j);
#pragma unroll
      for (int i = 0; i < 8; ++i) {
        float f = bf2f((u16)v[i]);
        s = fmaf(f, f, s);
      }
    }
    mx = fmaxf(mx, s);
  }
  red[tid] = mx;
  __syncthreads();
  for (int s2 = 128; s2 > 0; s2 >>= 1) {
    if (tid < s2) red[tid] = fmaxf(red[tid], red[tid + s2]);
    __syncthreads();
  }
  if (tid == 0) kmaxn[bh] = sqrtf(red[0]);
}

// ---------------- MFMA flash attention: static-bound softmax, l via ones-MFMA ----------------
#define LDW 72
#define SCL 0.18033688f   // (1/sqrt(64)) * log2(e); softmax in exp2 domain

__global__ __launch_bounds__(256) void attn_kernel(
    const u16* __restrict__ qb, const u16* __restrict__ kb,
    const u16* __restrict__ vtb, const int* __restrict__ mask,
    const float* __restrict__ meanv, const float* __restrict__ kmaxn,
    u16* __restrict__ outb)
{
  __shared__ u16 Ks[64 * LDW];       // K tile [key][d]
  __shared__ u16 Vs[64 * LDW];       // V^T tile [d][key]
  __shared__ u16 Ps[4][16 * LDW];    // per-wave P [row][key]

  int tid = threadIdx.x;
  int lane = tid & 63;
  int w = tid >> 6;
  int c = lane & 15;
  int q4 = lane >> 4;

  int pair = blockIdx.x & 7;
  int bh = blockIdx.x >> 3;
  int b = bh / NH;
  int h = bh - b * NH;
  float kmax = kmaxn[bh];

  int srow = tid >> 2;
  int schunk = (tid & 3) << 4;
  const u16* kgp = kb + ((size_t)bh * TT + srow) * HD + schunk;
  const u16* vgp = vtb + ((size_t)bh * HD + srow) * TT + schunk;
  u16* ksw = &Ks[srow * LDW + schunk];
  u16* vsw = &Vs[srow * LDW + schunk];
  u16* pw = &Ps[w][0];

  short8v onesv;
#pragma unroll
  for (int j = 0; j < 8; ++j) onesv[j] = (short)0x3F80;   // bf16 1.0

#pragma unroll 1
  for (int phase = 0; phase < 2; ++phase) {
    int qt = phase ? (15 - pair) : pair;
    int rowbase = (qt << 6) + (w << 4);

    short8v qfrag[2];
    {
      const u16* qp = qb + ((size_t)bh * TT + rowbase + c) * HD + q4 * 8;
      qfrag[0] = *(const short8v*)qp;
      qfrag[1] = *(const short8v*)(qp + 32);
    }

    // static per-row bound (exp2 domain): M = ||q_row|| * kmax * SCL >= s*SCL
    float q2 = 0.f;
#pragma unroll
    for (int kc = 0; kc < 2; ++kc)
#pragma unroll
      for (int j = 0; j < 8; ++j) {
        float qv = bf2f((u16)qfrag[kc][j]);
        q2 = fmaf(qv, qv, q2);
      }
    q2 += __shfl_xor(q2, 16);
    q2 += __shfl_xor(q2, 32);
    float Mc = sqrtf(q2) * kmax * SCL;
    float Mrow[4];
#pragma unroll
    for (int r = 0; r < 4; ++r) Mrow[r] = __shfl(Mc, (q4 << 2) + r);

    floatx4 o[4];
#pragma unroll
    for (int i = 0; i < 4; ++i) o[i] = (floatx4){0.f, 0.f, 0.f, 0.f};
    floatx4 o5 = (floatx4){0.f, 0.f, 0.f, 0.f};   // row-sum accumulator (l)

    short8v kr0, kr1, vr0, vr1;
    kr0 = *(const short8v*)kgp;
    kr1 = *(const short8v*)(kgp + 8);
    vr0 = *(const short8v*)vgp;
    vr1 = *(const short8v*)(vgp + 8);

#pragma unroll 1
    for (int kt = 0; kt <= qt; ++kt) {
      __syncthreads();
      *(short8v*)ksw = kr0; *(short8v*)(ksw + 8) = kr1;
      *(short8v*)vsw = vr0; *(short8v*)(vsw + 8) = vr1;
      __syncthreads();

      if (kt < qt) {
        const u16* kp = kgp + ((size_t)(kt + 1) << 6) * HD;
        const u16* vp = vgp + ((kt + 1) << 6);
        kr0 = *(const short8v*)kp;
        kr1 = *(const short8v*)(kp + 8);
        vr0 = *(const short8v*)vp;
        vr1 = *(const short8v*)(vp + 8);
      }

      floatx4 s[4];
#pragma unroll
      for (int nt = 0; nt < 4; ++nt) s[nt] = (floatx4){0.f, 0.f, 0.f, 0.f};
#pragma unroll
      for (int kc = 0; kc < 2; ++kc) {
#pragma unroll
        for (int nt = 0; nt < 4; ++nt) {
          short8v kf = *(const short8v*)&Ks[(nt * 16 + c) * LDW + kc * 32 + q4 * 8];
          s[nt] = __builtin_amdgcn_mfma_f32_16x16x32_bf16(qfrag[kc], kf, s[nt], 0, 0, 0);
        }
      }

      // p = exp2(s*SCL - M); causal kill on diag tile; write P (bf16) to wave-private LDS
      if (kt == qt) {
#pragma unroll
        for (int nt = 0; nt < 4; ++nt)
#pragma unroll
          for (int r = 0; r < 4; ++r) {
            float sv = s[nt][r];
            if (nt * 16 + c > (w << 4) + q4 * 4 + r) sv = -INFINITY;
            float p = fast_exp2(fmaf(sv, SCL, -Mrow[r]));
            pw[(q4 * 4 + r) * LDW + nt * 16 + c] = f2bf(p);
          }
      } else {
#pragma unroll
        for (int nt = 0; nt < 4; ++nt)
#pragma unroll
          for (int r = 0; r < 4; ++r) {
            float p = fast_exp2(fmaf(s[nt][r], SCL, -Mrow[r]));
            pw[(q4 * 4 + r) * LDW + nt * 16 + c] = f2bf(p);
          }
      }

      // PV + row-sum: O += P*Vt, l += P*1   (P wave-private, no barrier)
#pragma unroll
      for (int kc = 0; kc < 2; ++kc) {
        short8v pf = *(const short8v*)&pw[c * LDW + kc * 32 + q4 * 8];
#pragma unroll
        for (int nt = 0; nt < 4; ++nt) {
          short8v vf = *(const short8v*)&Vs[(nt * 16 + c) * LDW + kc * 32 + q4 * 8];
          o[nt] = __builtin_amdgcn_mfma_f32_16x16x32_bf16(pf, vf, o[nt], 0, 0, 0);
        }
        o5 = __builtin_amdgcn_mfma_f32_16x16x32_bf16(pf, onesv, o5, 0, 0, 0);
      }
    }

    int qrow[4]; bool msk[4]; float inv[4];
#pragma unroll
    for (int r = 0; r < 4; ++r) {
      qrow[r] = rowbase + q4 * 4 + r;
      msk[r] = (mask[b * TT + qrow[r]] == 0);
      inv[r] = 1.f / o5[r];
    }
#pragma unroll
    for (int nt = 0; nt < 4; ++nt) {
      int d = nt * 16 + c;
      float mv = meanv[bh * HD + d];
#pragma unroll
      for (int r = 0; r < 4; ++r) {
        float val = msk[r] ? mv : o[nt][r] * inv[r];
        outb[((size_t)(b * TT + qrow[r])) * CC + h * HD + d] = f2bf(val);
      }
    }
  }
}

// ---------------- launcher ----------------
extern "C" void kernel_launch(void* const* d_in, const int* in_sizes, int n_in,
                              void* d_out, int out_size, void* d_ws, size_t ws_size,
                              hipStream_t stream)
{
  (void)in_sizes; (void)n_in; (void)out_size; (void)ws_size;
  const float* x     = (const float*)d_in[0];
  const int*   mask  = (const int*)d_in[1];
  const float* Wattn = (const float*)d_in[2];
  const float* battn = (const float*)d_in[3];
  const float* Wproj = (const float*)d_in[4];
  const float* bproj = (const float*)d_in[5];
  float* out = (float*)d_out;

  char* ws = (char*)d_ws;
  size_t off = 0;
  auto alloc = [&](size_t bytes) -> void* {
    void* p = ws + off;
    off += (bytes + 255) & ~(size_t)255;
    return p;
  };
  u16* WtA  = (u16*)alloc((size_t)NQKV * KD * 2);
  u16* WtP  = (u16*)alloc((size_t)CC * CC * 2);
  u16* xb   = (u16*)alloc((size_t)MROWS * CC * 2);
  u16* qbuf = (u16*)alloc((size_t)MROWS * CC * 2);
  u16* kbuf = (u16*)alloc((size_t)MROWS * CC * 2);
  u16* vbuf = (u16*)alloc((size_t)MROWS * CC * 2);
  u16* vtb  = (u16*)alloc((size_t)MROWS * CC * 2);   // [bh][d][t]
  u16* abuf = (u16*)alloc((size_t)MROWS * CC * 2);
  float* mv = (float*)alloc((size_t)BH * HD * 4);
  float* kmx = (float*)alloc((size_t)BH * 4);

  int nx = MROWS * CC;
  convert_f32_bf16<<<nx / (256 * 4), 256, 0, stream>>>(x, xb, nx);
  transpose_f32_bf16<<<(NQKV/32)*(KD/32), 256, 0, stream>>>(Wattn, WtA, KD, NQKV);
  transpose_f32_bf16<<<(CC/32)*(CC/32),   256, 0, stream>>>(Wproj, WtP, CC, CC);

  gemm_bt<<<(MROWS/64)*(NQKV/128), 256, 0, stream>>>(
      xb, WtA, battn, nullptr, qbuf, kbuf, vbuf, MROWS, NQKV, 0);

  transpose_v<<<BH * (TT/64), 256, 0, stream>>>(vbuf, vtb);
  vmean_kernel<<<BH, 64, 0, stream>>>(vbuf, mv);
  knorm_kernel<<<BH, 256, 0, stream>>>(kbuf, kmx);

  attn_kernel<<<BH * 8, 256, 0, stream>>>(qbuf, kbuf, vtb, mask, mv, kmx, abuf);

  gemm_bt<<<(MROWS/64)*(CC/128), 256, 0, stream>>>(
      abuf, WtP, bproj, out, nullptr, nullptr, nullptr, MROWS, CC, 1);
}

// Round 10
// 211.397 us; speedup vs baseline: 3.6740x; 1.0130x over previous
//
#include <hip/hip_runtime.h>

#define BQ 8
#define TT 1024
#define CC 768
#define NH 12
#define HD 64
#define BH (BQ*NH)      // 96
#define MROWS (BQ*TT)   // 8192
#define NQKV (3*CC)     // 2304
#define KD CC           // 768

typedef unsigned short u16;
typedef __attribute__((ext_vector_type(4))) short short4v;
typedef __attribute__((ext_vector_type(8))) short short8v;
typedef __attribute__((ext_vector_type(4))) float floatx4;
typedef __attribute__((address_space(1))) const unsigned int gu32;
typedef __attribute__((address_space(3))) unsigned int lu32;

__device__ __forceinline__ float bf2f(u16 u) {
  union { unsigned int i; float f; } c; c.i = ((unsigned int)u) << 16; return c.f;
}
__device__ __forceinline__ u16 f2bf(float f) {
  union { float f; unsigned int i; } c; c.f = f;
  unsigned int i = c.i;
  return (u16)((i + 0x7FFFu + ((i >> 16) & 1u)) >> 16);  // RNE
}
__device__ __forceinline__ float fast_exp2(float x) {
  return __builtin_amdgcn_exp2f(x);   // v_exp_f32 (base-2)
}
// async global->LDS, 16 B per lane; LDS dest = wave-uniform base + lane*16
__device__ __forceinline__ void async_ld16(const u16* g, u16* l) {
  __builtin_amdgcn_global_load_lds((gu32*)g, (lu32*)l, 16, 0, 0);
}

// ---------------- fused prep: x->bf16 convert + 2 weight transposes ----------------
// grid = 6144 (convert) + 1728 (Wattn^T) + 576 (Wproj^T) = 8448 blocks
#define PREP_CONV 6144
#define PREP_WA   1728

__global__ __launch_bounds__(256) void prep_kernel(
    const float* __restrict__ x, u16* __restrict__ xb,
    const float* __restrict__ Wattn, u16* __restrict__ WtA,
    const float* __restrict__ Wproj, u16* __restrict__ WtP)
{
  __shared__ float tile[32][33];
  int bid = blockIdx.x;
  int tid = threadIdx.x;
  if (bid < PREP_CONV) {
    int i = (bid * 256 + tid) * 4;
    floatx4 v = *(const floatx4*)(x + i);
    short4v o;
    o[0] = (short)f2bf(v[0]); o[1] = (short)f2bf(v[1]);
    o[2] = (short)f2bf(v[2]); o[3] = (short)f2bf(v[3]);
    *(short4v*)(xb + i) = o;
    return;
  }
  const float* in; u16* out; int R, Cc, b2;
  if (bid < PREP_CONV + PREP_WA) { in = Wattn; out = WtA; R = KD; Cc = NQKV; b2 = bid - PREP_CONV; }
  else                           { in = Wproj; out = WtP; R = CC; Cc = CC;   b2 = bid - PREP_CONV - PREP_WA; }
  int ct = Cc >> 5;
  int bx = b2 % ct;
  int by = b2 / ct;
  int tx = tid & 31;
  int ty = tid >> 5;    // 0..7
  int c0 = bx << 5, r0 = by << 5;
#pragma unroll
  for (int s = 0; s < 4; ++s)
    tile[ty + s*8][tx] = in[(size_t)(r0 + ty + s*8) * Cc + c0 + tx];
  __syncthreads();
#pragma unroll
  for (int s = 0; s < 4; ++s)
    out[(size_t)(c0 + ty + s*8) * R + r0 + tx] = f2bf(tile[tx][ty + s*8]);
}

// ------- GEMM: 64x128 tile, BK=64, global_load_lds + XOR bank swizzle -------
// mode 0: scatter q/k bf16 [bh][t][d], V DIRECTLY TRANSPOSED [bh][d][t]; mode 1: f32 out.
__global__ __launch_bounds__(256) void gemm_bt(
    const u16* __restrict__ A, const u16* __restrict__ Bt,
    const float* __restrict__ bias,
    float* __restrict__ out,
    u16* __restrict__ qo, u16* __restrict__ ko, u16* __restrict__ vo,
    int M, int N, int mode)
{
  __shared__ u16 As[64 * 64];    // [row][64k], swizzled units
  __shared__ u16 Bs[128 * 64];

  int tid = threadIdx.x;
  int lane = tid & 63;
  int w = tid >> 6;
  int c = lane & 15;     // fragment col
  int q4 = lane >> 4;    // quad

  int mtiles = M >> 6;
  int mt = blockIdx.x % mtiles;
  int nt = blockIdx.x / mtiles;
  int m0 = mt << 6, n0 = nt << 7;

  int wr = (w >> 1) << 5;   // 0 / 32
  int wc = (w & 1) << 6;    // 0 / 64

  int srow8 = lane >> 3;                      // 0..7
  int ug = ((lane & 7) ^ srow8) << 3;         // swizzled global k-offset (shorts)
  const u16* ag = A  + (size_t)(m0 + w * 16 + srow8) * KD + ug;
  const u16* bg = Bt + (size_t)(n0 + w * 32 + srow8) * KD + ug;
  u16* asl = &As[(w * 16) * 64];
  u16* bsl = &Bs[(w * 32) * 64];

  floatx4 acc[2][4];
#pragma unroll
  for (int mi = 0; mi < 2; ++mi)
#pragma unroll
    for (int ni = 0; ni < 4; ++ni) acc[mi][ni] = (floatx4){0.f, 0.f, 0.f, 0.f};

  int c7 = c & 7;

#pragma unroll 1
  for (int kt = 0; kt < KD; kt += 64) {
    async_ld16(ag + kt,              asl);
    async_ld16(ag + kt + 8 * KD,     asl + 8 * 64);
    async_ld16(bg + kt,              bsl);
    async_ld16(bg + kt + 8 * KD,     bsl + 8 * 64);
    async_ld16(bg + kt + 16 * KD,    bsl + 16 * 64);
    async_ld16(bg + kt + 24 * KD,    bsl + 24 * 64);
    __syncthreads();

    short8v af[2][2], bf[4][2];
#pragma unroll
    for (int kc = 0; kc < 2; ++kc) {
      int uoff = ((kc * 4 + q4) ^ c7) << 3;
#pragma unroll
      for (int mi = 0; mi < 2; ++mi)
        af[mi][kc] = *(const short8v*)&As[(wr + mi * 16 + c) * 64 + uoff];
#pragma unroll
      for (int ni = 0; ni < 4; ++ni)
        bf[ni][kc] = *(const short8v*)&Bs[(wc + ni * 16 + c) * 64 + uoff];
    }
#pragma unroll
    for (int kc = 0; kc < 2; ++kc)
#pragma unroll
      for (int mi = 0; mi < 2; ++mi)
#pragma unroll
        for (int ni = 0; ni < 4; ++ni)
          acc[mi][ni] = __builtin_amdgcn_mfma_f32_16x16x32_bf16(af[mi][kc], bf[ni][kc], acc[mi][ni], 0, 0, 0);
    __syncthreads();
  }

  if (mode == 0) {
    int which = (n0 + wc) / CC;
    int nbase = (n0 + wc) - which * CC;
    u16* dst0 = (which == 0) ? qo : ((which == 1) ? ko : vo);
#pragma unroll
    for (int ni = 0; ni < 4; ++ni) {
      int nn = nbase + ni * 16 + c;
      int hh = nn >> 6, dd = nn & 63;
      float bv = bias[which * CC + nn];
#pragma unroll
      for (int mi = 0; mi < 2; ++mi) {
#pragma unroll
        for (int r = 0; r < 4; ++r) {
          int mm = m0 + wr + mi * 16 + q4 * 4 + r;
          int bb = mm >> 10, tt = mm & 1023;
          size_t bh = (size_t)(bb * NH + hh);
          size_t idx = (which == 2) ? (bh * HD + dd) * TT + tt    // V^T [bh][d][t]
                                    : (bh * TT + tt) * HD + dd;   // Q/K [bh][t][d]
          dst0[idx] = f2bf(acc[mi][ni][r] + bv);
        }
      }
    }
  } else {
#pragma unroll
    for (int ni = 0; ni < 4; ++ni) {
      int nn = n0 + wc + ni * 16 + c;
      float bv = bias[nn];
#pragma unroll
      for (int mi = 0; mi < 2; ++mi) {
#pragma unroll
        for (int r = 0; r < 4; ++r) {
          int mm = m0 + wr + mi * 16 + q4 * 4 + r;
          out[(size_t)mm * N + nn] = acc[mi][ni][r] + bv;
        }
      }
    }
  }
}

// ---------------- fused V-mean (from vtb rows) + max ||k_t|| per bh ----------------
__global__ __launch_bounds__(256) void vk_stats(
    const u16* __restrict__ vtb, const u16* __restrict__ kb,
    float* __restrict__ mv, float* __restrict__ kmaxn)
{
  __shared__ float red[256];
  int bh = blockIdx.x;
  int tid = threadIdx.x;
  int d = tid & 63;
  int g4 = tid >> 6;   // 0..3

  // vmean: vtb row (bh*64+d) is contiguous over t
  {
    const u16* vp = vtb + ((size_t)bh * HD + d) * TT + g4 * 256;
    float s = 0.f;
#pragma unroll 4
    for (int j = 0; j < 256; j += 8) {
      short8v v = *(const short8v*)(vp + j);
#pragma unroll
      for (int i = 0; i < 8; ++i) s += bf2f((u16)v[i]);
    }
    red[tid] = s;
  }
  __syncthreads();
  if (g4 == 0) mv[bh * HD + d] = (red[d] + red[d + 64] + red[d + 128] + red[d + 192]) * (1.0f / 1024.0f);
  __syncthreads();

  // knorm: max over t of ||k_t||^2
  float mx = 0.f;
#pragma unroll 1
  for (int t = tid; t < TT; t += 256) {
    const u16* p = kb + ((size_t)bh * TT + t) * HD;
    float ss = 0.f;
#pragma unroll
    for (int j = 0; j < 64; j += 8) {
      short8v v = *(const short8v*)(p + j);
#pragma unroll
      for (int i = 0; i < 8; ++i) {
        float f = bf2f((u16)v[i]);
        ss = fmaf(f, f, ss);
      }
    }
    mx = fmaxf(mx, ss);
  }
  red[tid] = mx;
  __syncthreads();
  for (int s2 = 128; s2 > 0; s2 >>= 1) {
    if (tid < s2) red[tid] = fmaxf(red[tid], red[tid + s2]);
    __syncthreads();
  }
  if (tid == 0) kmaxn[bh] = sqrtf(red[0]);
}

// ---------------- MFMA flash attention: S^T layout, static-bound softmax ----------------
// QK^T computed transposed (mfma(kf, qf)): lane owns q-row c, keys nt*16+q4*4+r
//  -> Mc needs no broadcast; P-write packs 4 consecutive keys per ds_write_b64.
// P LDS content [row][key] identical to prior verified layout; PV/ones-MFMA unchanged.
#define LDW 72
#define SCL 0.18033688f   // (1/sqrt(64)) * log2(e); softmax in exp2 domain

__global__ __launch_bounds__(256) void attn_kernel(
    const u16* __restrict__ qb, const u16* __restrict__ kb,
    const u16* __restrict__ vtb, const int* __restrict__ mask,
    const float* __restrict__ meanv, const float* __restrict__ kmaxn,
    u16* __restrict__ outb)
{
  __shared__ u16 Ks[64 * LDW];       // K tile [key][d]
  __shared__ u16 Vs[64 * LDW];       // V^T tile [d][key]
  __shared__ u16 Ps[4][16 * LDW];    // per-wave P [row][key]

  int tid = threadIdx.x;
  int lane = tid & 63;
  int w = tid >> 6;
  int c = lane & 15;
  int q4 = lane >> 4;

  int pair = blockIdx.x & 7;
  int bh = blockIdx.x >> 3;
  int b = bh / NH;
  int h = bh - b * NH;
  float kmax = kmaxn[bh];

  int srow = tid >> 2;
  int schunk = (tid & 3) << 4;
  const u16* kgp = kb + ((size_t)bh * TT + srow) * HD + schunk;
  const u16* vgp = vtb + ((size_t)bh * HD + srow) * TT + schunk;
  u16* ksw = &Ks[srow * LDW + schunk];
  u16* vsw = &Vs[srow * LDW + schunk];
  u16* pw = &Ps[w][0];

  short8v onesv;
#pragma unroll
  for (int j = 0; j < 8; ++j) onesv[j] = (short)0x3F80;   // bf16 1.0

#pragma unroll 1
  for (int phase = 0; phase < 2; ++phase) {
    int qt = phase ? (15 - pair) : pair;
    int rowbase = (qt << 6) + (w << 4);

    short8v qfrag[2];
    {
      const u16* qp = qb + ((size_t)bh * TT + rowbase + c) * HD + q4 * 8;
      qfrag[0] = *(const short8v*)qp;
      qfrag[1] = *(const short8v*)(qp + 32);
    }

    // static per-row bound (exp2 domain); lane owns row c -> no broadcast needed
    float q2 = 0.f;
#pragma unroll
    for (int kc = 0; kc < 2; ++kc)
#pragma unroll
      for (int j = 0; j < 8; ++j) {
        float qv = bf2f((u16)qfrag[kc][j]);
        q2 = fmaf(qv, qv, q2);
      }
    q2 += __shfl_xor(q2, 16);
    q2 += __shfl_xor(q2, 32);
    float Mc = sqrtf(q2) * kmax * SCL;

    floatx4 o[4];
#pragma unroll
    for (int i = 0; i < 4; ++i) o[i] = (floatx4){0.f, 0.f, 0.f, 0.f};
    floatx4 o5 = (floatx4){0.f, 0.f, 0.f, 0.f};   // row-sum accumulator (l)

    short8v kr0, kr1, vr0, vr1;
    kr0 = *(const short8v*)kgp;
    kr1 = *(const short8v*)(kgp + 8);
    vr0 = *(const short8v*)vgp;
    vr1 = *(const short8v*)(vgp + 8);

#pragma unroll 1
    for (int kt = 0; kt <= qt; ++kt) {
      __syncthreads();
      *(short8v*)ksw = kr0; *(short8v*)(ksw + 8) = kr1;
      *(short8v*)vsw = vr0; *(short8v*)(vsw + 8) = vr1;
      __syncthreads();

      if (kt < qt) {
        const u16* kp = kgp + ((size_t)(kt + 1) << 6) * HD;
        const u16* vp = vgp + ((kt + 1) << 6);
        kr0 = *(const short8v*)kp;
        kr1 = *(const short8v*)(kp + 8);
        vr0 = *(const short8v*)vp;
        vr1 = *(const short8v*)(vp + 8);
      }

      // S^T: s[nt] holds S[key=nt*16+q4*4+r][qrow=c]
      floatx4 s[4];
#pragma unroll
      for (int nt = 0; nt < 4; ++nt) s[nt] = (floatx4){0.f, 0.f, 0.f, 0.f};
#pragma unroll
      for (int kc = 0; kc < 2; ++kc) {
#pragma unroll
        for (int nt = 0; nt < 4; ++nt) {
          short8v kf = *(const short8v*)&Ks[(nt * 16 + c) * LDW + kc * 32 + q4 * 8];
          s[nt] = __builtin_amdgcn_mfma_f32_16x16x32_bf16(kf, qfrag[kc], s[nt], 0, 0, 0);
        }
      }

      // p = exp2(s*SCL - Mc); causal kill on diag tile; packed b64 P-writes
      int qrl = (w << 4) + c;   // local q-row within 64-tile
#pragma unroll
      for (int nt = 0; nt < 4; ++nt) {
        short4v pk;
#pragma unroll
        for (int r = 0; r < 4; ++r) {
          float sv = s[nt][r];
          if (kt == qt && (nt * 16 + (q4 << 2) + r > qrl)) sv = -INFINITY;
          pk[r] = (short)f2bf(fast_exp2(fmaf(sv, SCL, -Mc)));
        }
        *(short4v*)&pw[c * LDW + nt * 16 + (q4 << 2)] = pk;
      }

      // PV + row-sum: O += P*Vt, l += P*1   (P wave-private, no barrier)
#pragma unroll
      for (int kc = 0; kc < 2; ++kc) {
        short8v pf = *(const short8v*)&pw[c * LDW + kc * 32 + q4 * 8];
#pragma unroll
        for (int nt = 0; nt < 4; ++nt) {
          short8v vf = *(const short8v*)&Vs[(nt * 16 + c) * LDW + kc * 32 + q4 * 8];
          o[nt] = __builtin_amdgcn_mfma_f32_16x16x32_bf16(pf, vf, o[nt], 0, 0, 0);
        }
        o5 = __builtin_amdgcn_mfma_f32_16x16x32_bf16(pf, onesv, o5, 0, 0, 0);
      }
    }

    int qrow[4]; bool msk[4]; float inv[4];
#pragma unroll
    for (int r = 0; r < 4; ++r) {
      qrow[r] = rowbase + q4 * 4 + r;
      msk[r] = (mask[b * TT + qrow[r]] == 0);
      inv[r] = 1.f / o5[r];
    }
#pragma unroll
    for (int nt = 0; nt < 4; ++nt) {
      int d = nt * 16 + c;
      float mv = meanv[bh * HD + d];
#pragma unroll
      for (int r = 0; r < 4; ++r) {
        float val = msk[r] ? mv : o[nt][r] * inv[r];
        outb[((size_t)(b * TT + qrow[r])) * CC + h * HD + d] = f2bf(val);
      }
    }
  }
}

// ---------------- launcher ----------------
extern "C" void kernel_launch(void* const* d_in, const int* in_sizes, int n_in,
                              void* d_out, int out_size, void* d_ws, size_t ws_size,
                              hipStream_t stream)
{
  (void)in_sizes; (void)n_in; (void)out_size; (void)ws_size;
  const float* x     = (const float*)d_in[0];
  const int*   mask  = (const int*)d_in[1];
  const float* Wattn = (const float*)d_in[2];
  const float* battn = (const float*)d_in[3];
  const float* Wproj = (const float*)d_in[4];
  const float* bproj = (const float*)d_in[5];
  float* out = (float*)d_out;

  char* ws = (char*)d_ws;
  size_t off = 0;
  auto alloc = [&](size_t bytes) -> void* {
    void* p = ws + off;
    off += (bytes + 255) & ~(size_t)255;
    return p;
  };
  u16* WtA  = (u16*)alloc((size_t)NQKV * KD * 2);
  u16* WtP  = (u16*)alloc((size_t)CC * CC * 2);
  u16* xb   = (u16*)alloc((size_t)MROWS * CC * 2);
  u16* qbuf = (u16*)alloc((size_t)MROWS * CC * 2);
  u16* kbuf = (u16*)alloc((size_t)MROWS * CC * 2);
  u16* vtb  = (u16*)alloc((size_t)MROWS * CC * 2);   // V^T [bh][d][t], written by gemm
  u16* abuf = (u16*)alloc((size_t)MROWS * CC * 2);
  float* mv = (float*)alloc((size_t)BH * HD * 4);
  float* kmx = (float*)alloc((size_t)BH * 4);

  prep_kernel<<<8448, 256, 0, stream>>>(x, xb, Wattn, WtA, Wproj, WtP);

  gemm_bt<<<(MROWS/64)*(NQKV/128), 256, 0, stream>>>(
      xb, WtA, battn, nullptr, qbuf, kbuf, vtb, MROWS, NQKV, 0);

  vk_stats<<<BH, 256, 0, stream>>>(vtb, kbuf, mv, kmx);

  attn_kernel<<<BH * 8, 256, 0, stream>>>(qbuf, kbuf, vtb, mask, mv, kmx, abuf);

  gemm_bt<<<(MROWS/64)*(CC/128), 256, 0, stream>>>(
      abuf, WtP, bproj, out, nullptr, nullptr, nullptr, MROWS, CC, 1);
}

// Round 11
// 198.722 us; speedup vs baseline: 3.9083x; 1.0638x over previous
//
#include <hip/hip_runtime.h>

#define BQ 8
#define TT 1024
#define CC 768
#define NH 12
#define HD 64
#define BH (BQ*NH)      // 96
#define MROWS (BQ*TT)   // 8192
#define NQKV (3*CC)     // 2304
#define KD CC           // 768

typedef unsigned short u16;
typedef __attribute__((ext_vector_type(4))) short short4v;
typedef __attribute__((ext_vector_type(8))) short short8v;
typedef __attribute__((ext_vector_type(4))) float floatx4;
typedef __attribute__((address_space(1))) const unsigned int gu32;
typedef __attribute__((address_space(3))) unsigned int lu32;

__device__ __forceinline__ float bf2f(u16 u) {
  union { unsigned int i; float f; } c; c.i = ((unsigned int)u) << 16; return c.f;
}
__device__ __forceinline__ u16 f2bf(float f) {
  union { float f; unsigned int i; } c; c.f = f;
  unsigned int i = c.i;
  return (u16)((i + 0x7FFFu + ((i >> 16) & 1u)) >> 16);  // RNE
}
__device__ __forceinline__ float fast_exp2(float x) {
  return __builtin_amdgcn_exp2f(x);   // v_exp_f32 (base-2)
}
// async global->LDS, 16 B per lane; LDS dest = wave-uniform base + lane*16
__device__ __forceinline__ void async_ld16(const u16* g, u16* l) {
  __builtin_amdgcn_global_load_lds((gu32*)g, (lu32*)l, 16, 0, 0);
}

// ---------------- fused prep: x->bf16 convert + 2 weight transposes ----------------
#define PREP_CONV 6144
#define PREP_WA   1728

__global__ __launch_bounds__(256) void prep_kernel(
    const float* __restrict__ x, u16* __restrict__ xb,
    const float* __restrict__ Wattn, u16* __restrict__ WtA,
    const float* __restrict__ Wproj, u16* __restrict__ WtP)
{
  __shared__ float tile[32][33];
  int bid = blockIdx.x;
  int tid = threadIdx.x;
  if (bid < PREP_CONV) {
    int i = (bid * 256 + tid) * 4;
    floatx4 v = *(const floatx4*)(x + i);
    short4v o;
    o[0] = (short)f2bf(v[0]); o[1] = (short)f2bf(v[1]);
    o[2] = (short)f2bf(v[2]); o[3] = (short)f2bf(v[3]);
    *(short4v*)(xb + i) = o;
    return;
  }
  const float* in; u16* out; int R, Cc, b2;
  if (bid < PREP_CONV + PREP_WA) { in = Wattn; out = WtA; R = KD; Cc = NQKV; b2 = bid - PREP_CONV; }
  else                           { in = Wproj; out = WtP; R = CC; Cc = CC;   b2 = bid - PREP_CONV - PREP_WA; }
  int ct = Cc >> 5;
  int bx = b2 % ct;
  int by = b2 / ct;
  int tx = tid & 31;
  int ty = tid >> 5;    // 0..7
  int c0 = bx << 5, r0 = by << 5;
#pragma unroll
  for (int s = 0; s < 4; ++s)
    tile[ty + s*8][tx] = in[(size_t)(r0 + ty + s*8) * Cc + c0 + tx];
  __syncthreads();
#pragma unroll
  for (int s = 0; s < 4; ++s)
    out[(size_t)(c0 + ty + s*8) * R + r0 + tx] = f2bf(tile[tx][ty + s*8]);
}

// ------- GEMM: 64x128 tile, BK=64, global_load_lds + XOR bank swizzle -------
// mode 0: scatter q/k/v bf16 [bh][t][d]; mode 1: f32 row-major out.
__global__ __launch_bounds__(256) void gemm_bt(
    const u16* __restrict__ A, const u16* __restrict__ Bt,
    const float* __restrict__ bias,
    float* __restrict__ out,
    u16* __restrict__ qo, u16* __restrict__ ko, u16* __restrict__ vo,
    int M, int N, int mode)
{
  __shared__ u16 As[64 * 64];    // [row][64k], swizzled units
  __shared__ u16 Bs[128 * 64];

  int tid = threadIdx.x;
  int lane = tid & 63;
  int w = tid >> 6;
  int c = lane & 15;     // fragment col
  int q4 = lane >> 4;    // quad

  int mtiles = M >> 6;
  int mt = blockIdx.x % mtiles;
  int nt = blockIdx.x / mtiles;
  int m0 = mt << 6, n0 = nt << 7;

  int wr = (w >> 1) << 5;   // 0 / 32
  int wc = (w & 1) << 6;    // 0 / 64

  int srow8 = lane >> 3;                      // 0..7
  int ug = ((lane & 7) ^ srow8) << 3;         // swizzled global k-offset (shorts)
  const u16* ag = A  + (size_t)(m0 + w * 16 + srow8) * KD + ug;
  const u16* bg = Bt + (size_t)(n0 + w * 32 + srow8) * KD + ug;
  u16* asl = &As[(w * 16) * 64];
  u16* bsl = &Bs[(w * 32) * 64];

  floatx4 acc[2][4];
#pragma unroll
  for (int mi = 0; mi < 2; ++mi)
#pragma unroll
    for (int ni = 0; ni < 4; ++ni) acc[mi][ni] = (floatx4){0.f, 0.f, 0.f, 0.f};

  int c7 = c & 7;

#pragma unroll 1
  for (int kt = 0; kt < KD; kt += 64) {
    async_ld16(ag + kt,              asl);
    async_ld16(ag + kt + 8 * KD,     asl + 8 * 64);
    async_ld16(bg + kt,              bsl);
    async_ld16(bg + kt + 8 * KD,     bsl + 8 * 64);
    async_ld16(bg + kt + 16 * KD,    bsl + 16 * 64);
    async_ld16(bg + kt + 24 * KD,    bsl + 24 * 64);
    __syncthreads();

    short8v af[2][2], bf[4][2];
#pragma unroll
    for (int kc = 0; kc < 2; ++kc) {
      int uoff = ((kc * 4 + q4) ^ c7) << 3;
#pragma unroll
      for (int mi = 0; mi < 2; ++mi)
        af[mi][kc] = *(const short8v*)&As[(wr + mi * 16 + c) * 64 + uoff];
#pragma unroll
      for (int ni = 0; ni < 4; ++ni)
        bf[ni][kc] = *(const short8v*)&Bs[(wc + ni * 16 + c) * 64 + uoff];
    }
#pragma unroll
    for (int kc = 0; kc < 2; ++kc)
#pragma unroll
      for (int mi = 0; mi < 2; ++mi)
#pragma unroll
        for (int ni = 0; ni < 4; ++ni)
          acc[mi][ni] = __builtin_amdgcn_mfma_f32_16x16x32_bf16(af[mi][kc], bf[ni][kc], acc[mi][ni], 0, 0, 0);
    __syncthreads();
  }

  if (mode == 0) {
    int which = (n0 + wc) / CC;
    int nbase = (n0 + wc) - which * CC;
    u16* dst0 = (which == 0) ? qo : ((which == 1) ? ko : vo);
#pragma unroll
    for (int ni = 0; ni < 4; ++ni) {
      int nn = nbase + ni * 16 + c;
      int hh = nn >> 6, dd = nn & 63;
      float bv = bias[which * CC + nn];
#pragma unroll
      for (int mi = 0; mi < 2; ++mi) {
#pragma unroll
        for (int r = 0; r < 4; ++r) {
          int mm = m0 + wr + mi * 16 + q4 * 4 + r;
          int bb = mm >> 10, tt = mm & 1023;
          size_t idx = (((size_t)(bb * NH + hh)) * TT + tt) * HD + dd;
          dst0[idx] = f2bf(acc[mi][ni][r] + bv);
        }
      }
    }
  } else {
#pragma unroll
    for (int ni = 0; ni < 4; ++ni) {
      int nn = n0 + wc + ni * 16 + c;
      float bv = bias[nn];
#pragma unroll
      for (int mi = 0; mi < 2; ++mi) {
#pragma unroll
        for (int r = 0; r < 4; ++r) {
          int mm = m0 + wr + mi * 16 + q4 * 4 + r;
          out[(size_t)mm * N + nn] = acc[mi][ni][r] + bv;
        }
      }
    }
  }
}

// ---------------- V transpose: vbuf [bh][t][d] -> vtb [bh][d][t] ----------------
__global__ __launch_bounds__(256) void transpose_v(
    const u16* __restrict__ vb, u16* __restrict__ vt)
{
  __shared__ u16 tile[64][72];
  int tid = threadIdx.x;
  int tt0 = (blockIdx.x & 15) << 6;
  int bh = blockIdx.x >> 4;
  {
    int trow = tid >> 2;
    int dchunk = (tid & 3) << 4;
    const u16* src = vb + (((size_t)bh * TT + tt0 + trow) * HD) + dchunk;
    *(short8v*)&tile[trow][dchunk]     = *(const short8v*)src;
    *(short8v*)&tile[trow][dchunk + 8] = *(const short8v*)(src + 8);
  }
  __syncthreads();
  {
    int drow = tid >> 2;
    int tchunk = (tid & 3) << 4;
    short8v a, bv;
#pragma unroll
    for (int j = 0; j < 8; ++j) {
      a[j]  = (short)tile[tchunk + j][drow];
      bv[j] = (short)tile[tchunk + 8 + j][drow];
    }
    u16* dst = vt + ((size_t)bh * HD + drow) * TT + tt0 + tchunk;
    *(short8v*)dst       = a;
    *(short8v*)(dst + 8) = bv;
  }
}

// ---------------- fused V-mean (from vtb rows) + max ||k_t|| per bh ----------------
__global__ __launch_bounds__(256) void vk_stats(
    const u16* __restrict__ vtb, const u16* __restrict__ kb,
    float* __restrict__ mv, float* __restrict__ kmaxn)
{
  __shared__ float red[256];
  int bh = blockIdx.x;
  int tid = threadIdx.x;
  int d = tid & 63;
  int g4 = tid >> 6;   // 0..3

  // vmean: vtb row (bh*64+d) is contiguous over t
  {
    const u16* vp = vtb + ((size_t)bh * HD + d) * TT + g4 * 256;
    float s = 0.f;
#pragma unroll 4
    for (int j = 0; j < 256; j += 8) {
      short8v v = *(const short8v*)(vp + j);
#pragma unroll
      for (int i = 0; i < 8; ++i) s += bf2f((u16)v[i]);
    }
    red[tid] = s;
  }
  __syncthreads();
  if (g4 == 0) mv[bh * HD + d] = (red[d] + red[d + 64] + red[d + 128] + red[d + 192]) * (1.0f / 1024.0f);
  __syncthreads();

  // knorm: max over t of ||k_t||^2
  float mx = 0.f;
#pragma unroll 1
  for (int t = tid; t < TT; t += 256) {
    const u16* p = kb + ((size_t)bh * TT + t) * HD;
    float ss = 0.f;
#pragma unroll
    for (int j = 0; j < 64; j += 8) {
      short8v v = *(const short8v*)(p + j);
#pragma unroll
      for (int i = 0; i < 8; ++i) {
        float f = bf2f((u16)v[i]);
        ss = fmaf(f, f, ss);
      }
    }
    mx = fmaxf(mx, ss);
  }
  red[tid] = mx;
  __syncthreads();
  for (int s2 = 128; s2 > 0; s2 >>= 1) {
    if (tid < s2) red[tid] = fmaxf(red[tid], red[tid + s2]);
    __syncthreads();
  }
  if (tid == 0) kmaxn[bh] = sqrtf(red[0]);
}

// ---------------- MFMA flash attention: S^T layout, static-bound softmax ----------------
// QK^T computed transposed (mfma(kf, qf)): lane owns q-row c, keys nt*16+q4*4+r
//  -> Mc needs no broadcast; P-write packs 4 consecutive keys per ds_write_b64.
#define LDW 72
#define SCL 0.18033688f   // (1/sqrt(64)) * log2(e); softmax in exp2 domain

__global__ __launch_bounds__(256) void attn_kernel(
    const u16* __restrict__ qb, const u16* __restrict__ kb,
    const u16* __restrict__ vtb, const int* __restrict__ mask,
    const float* __restrict__ meanv, const float* __restrict__ kmaxn,
    u16* __restrict__ outb)
{
  __shared__ u16 Ks[64 * LDW];       // K tile [key][d]
  __shared__ u16 Vs[64 * LDW];       // V^T tile [d][key]
  __shared__ u16 Ps[4][16 * LDW];    // per-wave P [row][key]

  int tid = threadIdx.x;
  int lane = tid & 63;
  int w = tid >> 6;
  int c = lane & 15;
  int q4 = lane >> 4;

  int pair = blockIdx.x & 7;
  int bh = blockIdx.x >> 3;
  int b = bh / NH;
  int h = bh - b * NH;
  float kmax = kmaxn[bh];

  int srow = tid >> 2;
  int schunk = (tid & 3) << 4;
  const u16* kgp = kb + ((size_t)bh * TT + srow) * HD + schunk;
  const u16* vgp = vtb + ((size_t)bh * HD + srow) * TT + schunk;
  u16* ksw = &Ks[srow * LDW + schunk];
  u16* vsw = &Vs[srow * LDW + schunk];
  u16* pw = &Ps[w][0];

  short8v onesv;
#pragma unroll
  for (int j = 0; j < 8; ++j) onesv[j] = (short)0x3F80;   // bf16 1.0

#pragma unroll 1
  for (int phase = 0; phase < 2; ++phase) {
    int qt = phase ? (15 - pair) : pair;
    int rowbase = (qt << 6) + (w << 4);

    short8v qfrag[2];
    {
      const u16* qp = qb + ((size_t)bh * TT + rowbase + c) * HD + q4 * 8;
      qfrag[0] = *(const short8v*)qp;
      qfrag[1] = *(const short8v*)(qp + 32);
    }

    // static per-row bound (exp2 domain); lane owns row c -> no broadcast needed
    float q2 = 0.f;
#pragma unroll
    for (int kc = 0; kc < 2; ++kc)
#pragma unroll
      for (int j = 0; j < 8; ++j) {
        float qv = bf2f((u16)qfrag[kc][j]);
        q2 = fmaf(qv, qv, q2);
      }
    q2 += __shfl_xor(q2, 16);
    q2 += __shfl_xor(q2, 32);
    float Mc = sqrtf(q2) * kmax * SCL;

    floatx4 o[4];
#pragma unroll
    for (int i = 0; i < 4; ++i) o[i] = (floatx4){0.f, 0.f, 0.f, 0.f};
    floatx4 o5 = (floatx4){0.f, 0.f, 0.f, 0.f};   // row-sum accumulator (l)

    short8v kr0, kr1, vr0, vr1;
    kr0 = *(const short8v*)kgp;
    kr1 = *(const short8v*)(kgp + 8);
    vr0 = *(const short8v*)vgp;
    vr1 = *(const short8v*)(vgp + 8);

#pragma unroll 1
    for (int kt = 0; kt <= qt; ++kt) {
      __syncthreads();
      *(short8v*)ksw = kr0; *(short8v*)(ksw + 8) = kr1;
      *(short8v*)vsw = vr0; *(short8v*)(vsw + 8) = vr1;
      __syncthreads();

      if (kt < qt) {
        const u16* kp = kgp + ((size_t)(kt + 1) << 6) * HD;
        const u16* vp = vgp + ((kt + 1) << 6);
        kr0 = *(const short8v*)kp;
        kr1 = *(const short8v*)(kp + 8);
        vr0 = *(const short8v*)vp;
        vr1 = *(const short8v*)(vp + 8);
      }

      // S^T: s[nt] holds S[key=nt*16+q4*4+r][qrow=c]
      floatx4 s[4];
#pragma unroll
      for (int nt = 0; nt < 4; ++nt) s[nt] = (floatx4){0.f, 0.f, 0.f, 0.f};
#pragma unroll
      for (int kc = 0; kc < 2; ++kc) {
#pragma unroll
        for (int nt = 0; nt < 4; ++nt) {
          short8v kf = *(const short8v*)&Ks[(nt * 16 + c) * LDW + kc * 32 + q4 * 8];
          s[nt] = __builtin_amdgcn_mfma_f32_16x16x32_bf16(kf, qfrag[kc], s[nt], 0, 0, 0);
        }
      }

      // p = exp2(s*SCL - Mc); causal kill on diag tile; packed b64 P-writes
      int qrl = (w << 4) + c;   // local q-row within 64-tile
#pragma unroll
      for (int nt = 0; nt < 4; ++nt) {
        short4v pk;
#pragma unroll
        for (int r = 0; r < 4; ++r) {
          float sv = s[nt][r];
          if (kt == qt && (nt * 16 + (q4 << 2) + r > qrl)) sv = -INFINITY;
          pk[r] = (short)f2bf(fast_exp2(fmaf(sv, SCL, -Mc)));
        }
        *(short4v*)&pw[c * LDW + nt * 16 + (q4 << 2)] = pk;
      }

      // PV + row-sum: O += P*Vt, l += P*1   (P wave-private, no barrier)
#pragma unroll
      for (int kc = 0; kc < 2; ++kc) {
        short8v pf = *(const short8v*)&pw[c * LDW + kc * 32 + q4 * 8];
#pragma unroll
        for (int nt = 0; nt < 4; ++nt) {
          short8v vf = *(const short8v*)&Vs[(nt * 16 + c) * LDW + kc * 32 + q4 * 8];
          o[nt] = __builtin_amdgcn_mfma_f32_16x16x32_bf16(pf, vf, o[nt], 0, 0, 0);
        }
        o5 = __builtin_amdgcn_mfma_f32_16x16x32_bf16(pf, onesv, o5, 0, 0, 0);
      }
    }

    int qrow[4]; bool msk[4]; float inv[4];
#pragma unroll
    for (int r = 0; r < 4; ++r) {
      qrow[r] = rowbase + q4 * 4 + r;
      msk[r] = (mask[b * TT + qrow[r]] == 0);
      inv[r] = 1.f / o5[r];
    }
#pragma unroll
    for (int nt = 0; nt < 4; ++nt) {
      int d = nt * 16 + c;
      float mv = meanv[bh * HD + d];
#pragma unroll
      for (int r = 0; r < 4; ++r) {
        float val = msk[r] ? mv : o[nt][r] * inv[r];
        outb[((size_t)(b * TT + qrow[r])) * CC + h * HD + d] = f2bf(val);
      }
    }
  }
}

// ---------------- launcher ----------------
extern "C" void kernel_launch(void* const* d_in, const int* in_sizes, int n_in,
                              void* d_out, int out_size, void* d_ws, size_t ws_size,
                              hipStream_t stream)
{
  (void)in_sizes; (void)n_in; (void)out_size; (void)ws_size;
  const float* x     = (const float*)d_in[0];
  const int*   mask  = (const int*)d_in[1];
  const float* Wattn = (const float*)d_in[2];
  const float* battn = (const float*)d_in[3];
  const float* Wproj = (const float*)d_in[4];
  const float* bproj = (const float*)d_in[5];
  float* out = (float*)d_out;

  char* ws = (char*)d_ws;
  size_t off = 0;
  auto alloc = [&](size_t bytes) -> void* {
    void* p = ws + off;
    off += (bytes + 255) & ~(size_t)255;
    return p;
  };
  u16* WtA  = (u16*)alloc((size_t)NQKV * KD * 2);
  u16* WtP  = (u16*)alloc((size_t)CC * CC * 2);
  u16* xb   = (u16*)alloc((size_t)MROWS * CC * 2);
  u16* qbuf = (u16*)alloc((size_t)MROWS * CC * 2);
  u16* kbuf = (u16*)alloc((size_t)MROWS * CC * 2);
  u16* vbuf = (u16*)alloc((size_t)MROWS * CC * 2);   // V [bh][t][d]
  u16* vtb  = (u16*)alloc((size_t)MROWS * CC * 2);   // V^T [bh][d][t]
  u16* abuf = (u16*)alloc((size_t)MROWS * CC * 2);
  float* mv = (float*)alloc((size_t)BH * HD * 4);
  float* kmx = (float*)alloc((size_t)BH * 4);

  prep_kernel<<<8448, 256, 0, stream>>>(x, xb, Wattn, WtA, Wproj, WtP);

  gemm_bt<<<(MROWS/64)*(NQKV/128), 256, 0, stream>>>(
      xb, WtA, battn, nullptr, qbuf, kbuf, vbuf, MROWS, NQKV, 0);

  transpose_v<<<BH * (TT/64), 256, 0, stream>>>(vbuf, vtb);
  vk_stats<<<BH, 256, 0, stream>>>(vtb, kbuf, mv, kmx);

  attn_kernel<<<BH * 8, 256, 0, stream>>>(qbuf, kbuf, vtb, mask, mv, kmx, abuf);

  gemm_bt<<<(MROWS/64)*(CC/128), 256, 0, stream>>>(
      abuf, WtP, bproj, out, nullptr, nullptr, nullptr, MROWS, CC, 1);
}